// Round 2
// 2560.951 us; speedup vs baseline: 2.5636x; 2.5636x over previous
//
#include <hip/hip_runtime.h>

#define KK 25
#define KRR 19
#define NH 4
#define GG 100
#define FFH 128

__device__ __constant__ int c_l_per_k[25] = {0, 1,1,1, 2,2,2,2,2,
                                             3,3,3,3,3,3,3,
                                             4,4,4,4,4,4,4,4,4};

__device__ __forceinline__ float siluf(float x) { return x / (1.0f + expf(-x)); }
__device__ __forceinline__ float sigmf(float x) { return 1.0f / (1.0f + expf(-x)); }

// compile-time l(k) for fully-unrolled loops
__device__ __forceinline__ constexpr int lpk(int k) {
    return (k == 0) ? 0 : (k < 4) ? 1 : (k < 9) ? 2 : (k < 16) ? 3 : 4;
}

// cross-lane extract on the VALU pipe (not LDS): v_readlane_b32
__device__ __forceinline__ float rdlane(float x, int l) {
    return __int_as_float(__builtin_amdgcn_readlane(__float_as_int(x), l));
}

// ---- k_scale: per-node RMS scale (f32) ----
__global__ void k_scale(const float* __restrict__ xf, float* __restrict__ scale) {
    int n = blockIdx.x, t = threadIdx.x;
    __shared__ float red[256];
    const float* xp = xf + (size_t)n * 1600;
    float ss = 0.f;
    for (int i = t; i < 1600; i += 256) { float v = xp[i]; ss += v * v; }
    red[t] = ss; __syncthreads();
    for (int s = 128; s > 0; s >>= 1) { if (t < s) red[t] += red[t + s]; __syncthreads(); }
    if (t == 0) scale[n] = rsqrtf(red[0] / 1600.0f + 1e-6f);
}

// ---- k_edge_logits: edge MLP + attention logits (normed x on the fly) ----
__global__ __launch_bounds__(128) void k_edge_logits(
        const float* __restrict__ edist, const float* __restrict__ emb_s,
        const float* __restrict__ emb_r, const float* __restrict__ We1,
        const float* __restrict__ We2, const float* __restrict__ Wso2,
        const float* __restrict__ Wa, const float* __restrict__ va,
        const float* __restrict__ wigner, const float* __restrict__ xf,
        const float* __restrict__ g1, const float* __restrict__ scale,
        const int* __restrict__ species, const int* __restrict__ senders,
        const int* __restrict__ receivers, float* __restrict__ logits) {
    int e = blockIdx.x, t = threadIdx.x;
    __shared__ float efin[128], h1[128], efs[64], xr0[128], msg0[64], ared[128];
    int s = senders[e], r = receivers[e];
    if (t < 64)       efin[t] = edist[(size_t)e * 64 + t];
    else if (t < 96)  efin[t] = emb_s[species[s] * 32 + (t - 64)];
    else              efin[t] = emb_r[species[r] * 32 + (t - 96)];
    {   // xr row 0 on the fly
        int c = t & 63;
        int node = (t < 64) ? s : r;
        float sc = scale[node];
        const float* xb = xf + (size_t)node * 1600;
        float a = 0.f;
        for (int k = 0; k < KK; ++k)
            a += wigner[(size_t)e * 475 + k] * xb[k * 64 + c] * g1[c_l_per_k[k] * 64 + c];
        xr0[t] = a * sc;
    }
    __syncthreads();
    {
        float a = 0.f;
        for (int c = 0; c < 128; ++c) a += efin[c] * We1[c * 128 + t];
        h1[t] = siluf(a);
    }
    __syncthreads();
    if (t < 64) {
        float a = 0.f;
        for (int c = 0; c < 128; ++c) a += h1[c] * We2[c * 64 + t];
        efs[t] = siluf(a);
    }
    __syncthreads();
    if (t < 64) {
        float a = 0.f;
        for (int c = 0; c < 128; ++c) a += xr0[c] * Wso2[c * 64 + t];
        a *= efs[t];
        msg0[t] = a * sigmf(a);
    }
    __syncthreads();
    {
        float a = 0.f;
        for (int d = 0; d < 64; ++d) a += msg0[d] * Wa[d * 128 + t];
        float av = (a > 0.f) ? a : 0.2f * a;
        ared[t] = av * va[t];
    }
    __syncthreads();
    if (t < NH) {
        float sum = 0.f;
        for (int a = 0; a < 32; ++a) sum += ared[t * 32 + a];
        logits[(size_t)e * NH + t] = sum;
    }
}

// ---- CSR build ----
__global__ void k_count(const int* __restrict__ receivers, int* __restrict__ counts, int E) {
    int e = blockIdx.x * blockDim.x + threadIdx.x;
    if (e < E) atomicAdd(&counts[receivers[e]], 1);
}

__global__ void k_scan(int* __restrict__ counts, int* __restrict__ offsets, int n) {
    __shared__ int buf[256];
    __shared__ int base_s;
    int t = threadIdx.x;
    if (t == 0) base_s = 0;
    __syncthreads();
    for (int start = 0; start < n; start += 256) {
        int idx = start + t;
        int v = (idx < n) ? counts[idx] : 0;
        buf[t] = v; __syncthreads();
        for (int o = 1; o < 256; o <<= 1) {
            int x = (t >= o) ? buf[t - o] : 0;
            __syncthreads();
            buf[t] += x;
            __syncthreads();
        }
        int incl = buf[t];
        int b = base_s;
        if (idx < n) { offsets[idx] = b + incl - v; counts[idx] = 0; }
        __syncthreads();
        if (t == 0) base_s = b + buf[255];
        __syncthreads();
    }
    if (t == 0) offsets[n] = base_s;
}

__global__ void k_fill(const int* __restrict__ receivers, const int* __restrict__ offsets,
                       int* __restrict__ cursors, int* __restrict__ edge_ids, int E) {
    int e = blockIdx.x * blockDim.x + threadIdx.x;
    if (e >= E) return;
    int r = receivers[e];
    int pos = atomicAdd(&cursors[r], 1);
    edge_ids[offsets[r] + pos] = e;
}

// ---- k_alpha: per-(node,head) softmax over incoming edges, alpha written
//      IN PLACE over logits (each edge has exactly one receiver -> no conflicts)
__global__ void k_alpha(float* __restrict__ logits, const int* __restrict__ offsets,
                        const int* __restrict__ edge_ids, int N) {
    int i = blockIdx.x * blockDim.x + threadIdx.x;
    if (i >= N * NH) return;
    int n = i >> 2, h = i & 3;
    int o0 = offsets[n], o1 = offsets[n + 1];
    float m = -1e30f;
    for (int j = o0; j < o1; ++j)
        m = fmaxf(m, logits[(size_t)edge_ids[j] * NH + h]);
    float s = 0.f;
    for (int j = o0; j < o1; ++j)
        s += expf(logits[(size_t)edge_ids[j] * NH + h] - m);
    float inv = 1.0f / (s + 1e-9f);
    for (int j = o0; j < o1; ++j) {
        size_t idx = (size_t)edge_ids[j] * NH + h;
        logits[idx] = expf(logits[idx] - m) * inv;
    }
}

// ---- k_tr_fg: transpose from_grid [K][G] -> [G][K] for contiguous uniform rows ----
__global__ void k_tr_fg(const float* __restrict__ from_grid, float* __restrict__ fgT) {
    int i = blockIdx.x * blockDim.x + threadIdx.x;
    if (i < GG * KK) {
        int g = i / KK, k = i - g * KK;
        fgT[g * KK + k] = from_grid[k * GG + g];
    }
}

// ---- k_edge: one WAVE per edge, zero LDS, zero barriers ----
// lane = channel (64). Per-lane data in regs; wave-uniform operands via s_load;
// transposes over the lane dim via v_readlane (VALU pipe, not LDS).
__global__ __launch_bounds__(256) void k_edge(
        const float* __restrict__ xf, const float* __restrict__ wigner,
        const float* __restrict__ wigner_inv, const float* __restrict__ edist,
        const float* __restrict__ emb_s, const float* __restrict__ emb_r,
        const float* __restrict__ We1, const float* __restrict__ We2,
        const float* __restrict__ Wso2, const float* __restrict__ Wv,
        const float* __restrict__ Wo, const float* __restrict__ g1,
        const float* __restrict__ scale, const float* __restrict__ alpha,
        const int* __restrict__ species, const int* __restrict__ senders,
        const int* __restrict__ receivers, float* __restrict__ out, int E) {
    const int lane = threadIdx.x & 63;
    const int e = __builtin_amdgcn_readfirstlane(blockIdx.x * 4 + (threadIdx.x >> 6));
    if (e >= E) return;
    const int s = senders[e];
    const int r = receivers[e];
    const float scs = scale[s], scr = scale[r];

    float g1l[5];
#pragma unroll
    for (int l = 0; l < 5; ++l) g1l[l] = g1[l * 64 + lane];

    // normed sender (xs) / receiver (xc) features, lane = channel
    float xs[25], xc[25];
#pragma unroll
    for (int k = 0; k < 25; ++k) {
        const float gk = g1l[lpk(k)];
        xs[k] = xf[(size_t)s * 1600 + k * 64 + lane] * scs * gk;
        xc[k] = xf[(size_t)r * 1600 + k * 64 + lane] * scr * gk;
    }

    // xr = wigner @ [xs | xc]  (wigner rows wave-uniform -> SGPR operand FMAs)
    const float* __restrict__ wge = wigner + (size_t)e * 475;
    float xrs[19], xrc[19];
#pragma unroll
    for (int rr = 0; rr < 19; ++rr) {
        float a = 0.f, b = 0.f;
#pragma unroll
        for (int k = 0; k < 25; ++k) {
            const float w = wge[rr * 25 + k];
            a += w * xs[k];
            b += w * xc[k];
        }
        xrs[rr] = a; xrc[rr] = b;
    }

    // invariant edge MLP: h1 = silu(efin @ We1); efs = silu(h1 @ We2)
    float h1a = 0.f, h1b = 0.f;
    {
        const float* __restrict__ eda = edist + (size_t)e * 64;
        const float* __restrict__ esa = emb_s + (size_t)species[s] * 32;
        const float* __restrict__ era = emb_r + (size_t)species[r] * 32;
        for (int c = 0; c < 64; ++c) {
            const float v = eda[c];
            h1a += v * We1[c * 128 + lane];
            h1b += v * We1[c * 128 + 64 + lane];
        }
        for (int c = 0; c < 32; ++c) {
            const float v = esa[c];
            h1a += v * We1[(64 + c) * 128 + lane];
            h1b += v * We1[(64 + c) * 128 + 64 + lane];
        }
        for (int c = 0; c < 32; ++c) {
            const float v = era[c];
            h1a += v * We1[(96 + c) * 128 + lane];
            h1b += v * We1[(96 + c) * 128 + 64 + lane];
        }
        h1a = siluf(h1a); h1b = siluf(h1b);
    }
    float efs = 0.f;
    for (int j = 0; j < 64; ++j) {
        efs += rdlane(h1a, j) * We2[j * 64 + lane];
        efs += rdlane(h1b, j) * We2[(j + 64) * 64 + lane];
    }
    efs = siluf(efs);

    // msg = (xr @ Wso2) * efs, then S2 gate with sigmoid of row 0
    float msg[19];
#pragma unroll
    for (int rr = 0; rr < 19; ++rr) msg[rr] = 0.f;
    for (int c = 0; c < 64; ++c) {
        const float w0 = Wso2[c * 64 + lane];
        const float w1 = Wso2[(64 + c) * 64 + lane];
#pragma unroll
        for (int rr = 0; rr < 19; ++rr)
            msg[rr] += rdlane(xrs[rr], c) * w0 + rdlane(xrc[rr], c) * w1;
    }
#pragma unroll
    for (int rr = 0; rr < 19; ++rr) msg[rr] *= efs;
    const float gate = sigmf(msg[0]);
#pragma unroll
    for (int rr = 0; rr < 19; ++rr) msg[rr] *= gate;

    // attention weight for this lane's head group (VC=16 -> h = lane>>4)
    const int hh = lane >> 4;
    const float al = alpha[(size_t)e * NH + hh];

    // v2 = (msg @ Wv) * alpha
    float v2[19];
#pragma unroll
    for (int rr = 0; rr < 19; ++rr) v2[rr] = 0.f;
    for (int d = 0; d < 64; ++d) {
        const float w = Wv[d * 64 + lane];
#pragma unroll
        for (int rr = 0; rr < 19; ++rr) v2[rr] += rdlane(msg[rr], d) * w;
    }
#pragma unroll
    for (int rr = 0; rr < 19; ++rr) v2[rr] *= al;

    // z = v2 @ Wo  (reassociated: expand 19 -> 25 rows LAST)
    float z[19];
#pragma unroll
    for (int rr = 0; rr < 19; ++rr) z[rr] = 0.f;
    for (int d = 0; d < 64; ++d) {
        const float w = Wo[d * 64 + lane];
#pragma unroll
        for (int rr = 0; rr < 19; ++rr) z[rr] += rdlane(v2[rr], d) * w;
    }

    // out[r] += wigner_inv @ z  (pure SGPR x VGPR FMAs + coalesced atomics)
    const float* __restrict__ wvi = wigner_inv + (size_t)e * 475;
    float* __restrict__ op = out + (size_t)r * 1600;
#pragma unroll
    for (int k = 0; k < 25; ++k) {
        float a = 0.f;
#pragma unroll
        for (int rr = 0; rr < 19; ++rr) a += wvi[k * 19 + rr] * z[rr];
        atomicAdd(&op[k * 64 + lane], a);
    }
}

// ---- k_ffn: one WAVE per node: residual + norm2 + S2-grid FFN, zero LDS ----
__global__ __launch_bounds__(256) void k_ffn(
        const float* __restrict__ xf, const float* __restrict__ g2,
        const float* __restrict__ to_grid, const float* __restrict__ fgT,
        const float* __restrict__ Wf1, const float* __restrict__ Wf2,
        float* __restrict__ out, int N) {
    const int lane = threadIdx.x & 63;
    const int n = __builtin_amdgcn_readfirstlane(blockIdx.x * 4 + (threadIdx.x >> 6));
    if (n >= N) return;
    const float* __restrict__ oin = out + (size_t)n * 1600;
    const float* __restrict__ xin = xf + (size_t)n * 1600;

    // X = attn_out + residual ; rms over all 1600
    float xn[25];
    float ss = 0.f;
#pragma unroll
    for (int k = 0; k < 25; ++k) {
        const float X = oin[k * 64 + lane] + xin[k * 64 + lane];
        xn[k] = X;
        ss += X * X;
    }
#pragma unroll
    for (int m = 1; m < 64; m <<= 1) ss += __shfl_xor(ss, m, 64);
    const float sc2 = rsqrtf(ss * (1.0f / 1600.f) + 1e-6f);
#pragma unroll
    for (int k = 0; k < 25; ++k) xn[k] *= sc2 * g2[lpk(k) * 64 + lane];

    float racc[25];
#pragma unroll
    for (int k = 0; k < 25; ++k) racc[k] = 0.f;

    for (int g0 = 0; g0 < GG; g0 += 10) {
        // xg[g] = to_grid row (uniform s_load) . xn   -- lane = channel
        float xg[10];
#pragma unroll
        for (int gg = 0; gg < 10; ++gg) {
            const float* __restrict__ tg = to_grid + (size_t)(g0 + gg) * KK;
            float a = 0.f;
#pragma unroll
            for (int k = 0; k < 25; ++k) a += tg[k] * xn[k];
            xg[gg] = a;
        }
        // h = silu(xg @ Wf1)  -- transpose over channel via readlane
        float ha[10], hb[10];
#pragma unroll
        for (int gg = 0; gg < 10; ++gg) { ha[gg] = 0.f; hb[gg] = 0.f; }
        for (int c = 0; c < 64; ++c) {
            const float w0 = Wf1[c * FFH + lane];
            const float w1 = Wf1[c * FFH + 64 + lane];
#pragma unroll
            for (int gg = 0; gg < 10; ++gg) {
                const float sv = rdlane(xg[gg], c);
                ha[gg] += sv * w0;
                hb[gg] += sv * w1;
            }
        }
#pragma unroll
        for (int gg = 0; gg < 10; ++gg) { ha[gg] = siluf(ha[gg]); hb[gg] = siluf(hb[gg]); }
        // og = h @ Wf2  -- transpose over hidden via readlane
        float og[10];
#pragma unroll
        for (int gg = 0; gg < 10; ++gg) og[gg] = 0.f;
        for (int j = 0; j < 64; ++j) {
            const float w0 = Wf2[j * 64 + lane];
            const float w1 = Wf2[(j + 64) * 64 + lane];
#pragma unroll
            for (int gg = 0; gg < 10; ++gg)
                og[gg] += rdlane(ha[gg], j) * w0 + rdlane(hb[gg], j) * w1;
        }
        // racc += from_grid^T rows (uniform s_load) * og
#pragma unroll
        for (int gg = 0; gg < 10; ++gg) {
            const float* __restrict__ fg = fgT + (size_t)(g0 + gg) * KK;
            const float o = og[gg];
#pragma unroll
            for (int k = 0; k < 25; ++k) racc[k] += fg[k] * o;
        }
    }
    float* __restrict__ op = out + (size_t)n * 1600;
#pragma unroll
    for (int k = 0; k < 25; ++k)
        op[k * 64 + lane] = oin[k * 64 + lane] + xin[k * 64 + lane] + racc[k];
}

extern "C" void kernel_launch(void* const* d_in, const int* in_sizes, int n_in,
                              void* d_out, int out_size, void* d_ws, size_t ws_size,
                              hipStream_t stream) {
    const float* node_feats     = (const float*)d_in[0];
    const float* edge_distances = (const float*)d_in[1];
    const float* wigner         = (const float*)d_in[2];
    const float* wigner_inv     = (const float*)d_in[3];
    const int*   node_species   = (const int*)  d_in[4];
    const int*   senders        = (const int*)  d_in[5];
    const int*   receivers      = (const int*)  d_in[6];
    const float* g1             = (const float*)d_in[7];
    const float* g2             = (const float*)d_in[8];
    const float* emb_s          = (const float*)d_in[9];
    const float* emb_r          = (const float*)d_in[10];
    const float* We1            = (const float*)d_in[11];
    const float* We2            = (const float*)d_in[12];
    const float* Wso2           = (const float*)d_in[13];
    const float* Wa             = (const float*)d_in[14];
    const float* va             = (const float*)d_in[15];
    const float* Wv             = (const float*)d_in[16];
    const float* Wo             = (const float*)d_in[17];
    const float* to_grid        = (const float*)d_in[18];
    const float* from_grid      = (const float*)d_in[19];
    const float* Wf1            = (const float*)d_in[20];
    const float* Wf2            = (const float*)d_in[21];

    const int N = in_sizes[4];
    const int E = in_sizes[5];

    char* ws = (char*)d_ws;
    size_t o = 0;
    float* scale    = (float*)(ws + o); o += (size_t)N * 4;
    int*   counts   = (int*)  (ws + o); o += (size_t)N * 4;
    int*   offsets  = (int*)  (ws + o); o += (size_t)(N + 1) * 4;
    int*   edge_ids = (int*)  (ws + o); o += (size_t)E * 4;
    float* logits   = (float*)(ws + o); o += (size_t)E * NH * 4;
    float* fgT      = (float*)(ws + o); o += (size_t)GG * KK * 4;
    // total ws use ~730 KB (same footprint as the verified baseline)

    hipMemsetAsync(counts, 0, (size_t)N * 4, stream);
    hipMemsetAsync(d_out, 0, (size_t)N * 1600 * 4, stream);

    k_scale<<<N, 256, 0, stream>>>(node_feats, scale);
    k_edge_logits<<<E, 128, 0, stream>>>(edge_distances, emb_s, emb_r, We1, We2, Wso2,
                                         Wa, va, wigner, node_feats, g1, scale,
                                         node_species, senders, receivers, logits);
    k_count<<<(E + 255) / 256, 256, 0, stream>>>(receivers, counts, E);
    k_scan<<<1, 256, 0, stream>>>(counts, offsets, N);
    k_fill<<<(E + 255) / 256, 256, 0, stream>>>(receivers, offsets, counts, edge_ids, E);
    k_alpha<<<(N * NH + 255) / 256, 256, 0, stream>>>(logits, offsets, edge_ids, N);
    k_tr_fg<<<(GG * KK + 255) / 256, 256, 0, stream>>>(from_grid, fgT);
    k_edge<<<(E + 3) / 4, 256, 0, stream>>>(node_feats, wigner, wigner_inv,
                                            edge_distances, emb_s, emb_r, We1, We2,
                                            Wso2, Wv, Wo, g1, scale, logits,
                                            node_species, senders, receivers,
                                            (float*)d_out, E);
    k_ffn<<<(N + 3) / 4, 256, 0, stream>>>(node_feats, g2, to_grid, fgT, Wf1, Wf2,
                                           (float*)d_out, N);
}

// Round 3
// 1944.550 us; speedup vs baseline: 3.3763x; 1.3170x over previous
//
#include <hip/hip_runtime.h>

#define KK 25
#define KRR 19
#define NH 4
#define GG 100
#define FFH 128

__device__ __constant__ int c_l_per_k[25] = {0, 1,1,1, 2,2,2,2,2,
                                             3,3,3,3,3,3,3,
                                             4,4,4,4,4,4,4,4,4};

__device__ __forceinline__ float siluf(float x) { return x / (1.0f + __expf(-x)); }
__device__ __forceinline__ float sigmf(float x) { return 1.0f / (1.0f + __expf(-x)); }

// compile-time l(k) for fully-unrolled loops
__device__ __forceinline__ constexpr int lpk(int k) {
    return (k == 0) ? 0 : (k < 4) ? 1 : (k < 9) ? 2 : (k < 16) ? 3 : 4;
}

// cross-lane extract on the VALU pipe (not LDS): v_readlane_b32
__device__ __forceinline__ float rdlane(float x, int l) {
    return __int_as_float(__builtin_amdgcn_readlane(__float_as_int(x), l));
}

// ---- k_scale: per-node RMS scale (f32) ----
__global__ void k_scale(const float* __restrict__ xf, float* __restrict__ scale) {
    int n = blockIdx.x, t = threadIdx.x;
    __shared__ float red[256];
    const float* xp = xf + (size_t)n * 1600;
    float ss = 0.f;
    for (int i = t; i < 1600; i += 256) { float v = xp[i]; ss += v * v; }
    red[t] = ss; __syncthreads();
    for (int s = 128; s > 0; s >>= 1) { if (t < s) red[t] += red[t + s]; __syncthreads(); }
    if (t == 0) scale[n] = rsqrtf(red[0] / 1600.0f + 1e-6f);
}

// ---- k_edge_logits: edge MLP + attention logits (normed x on the fly) ----
__global__ __launch_bounds__(128) void k_edge_logits(
        const float* __restrict__ edist, const float* __restrict__ emb_s,
        const float* __restrict__ emb_r, const float* __restrict__ We1,
        const float* __restrict__ We2, const float* __restrict__ Wso2,
        const float* __restrict__ Wa, const float* __restrict__ va,
        const float* __restrict__ wigner, const float* __restrict__ xf,
        const float* __restrict__ g1, const float* __restrict__ scale,
        const int* __restrict__ species, const int* __restrict__ senders,
        const int* __restrict__ receivers, float* __restrict__ logits) {
    int e = blockIdx.x, t = threadIdx.x;
    __shared__ float efin[128], h1[128], efs[64], xr0[128], msg0[64], ared[128];
    int s = senders[e], r = receivers[e];
    if (t < 64)       efin[t] = edist[(size_t)e * 64 + t];
    else if (t < 96)  efin[t] = emb_s[species[s] * 32 + (t - 64)];
    else              efin[t] = emb_r[species[r] * 32 + (t - 96)];
    {   // xr row 0 on the fly
        int c = t & 63;
        int node = (t < 64) ? s : r;
        float sc = scale[node];
        const float* xb = xf + (size_t)node * 1600;
        float a = 0.f;
        for (int k = 0; k < KK; ++k)
            a += wigner[(size_t)e * 475 + k] * xb[k * 64 + c] * g1[c_l_per_k[k] * 64 + c];
        xr0[t] = a * sc;
    }
    __syncthreads();
    {
        float a = 0.f;
        for (int c = 0; c < 128; ++c) a += efin[c] * We1[c * 128 + t];
        h1[t] = siluf(a);
    }
    __syncthreads();
    if (t < 64) {
        float a = 0.f;
        for (int c = 0; c < 128; ++c) a += h1[c] * We2[c * 64 + t];
        efs[t] = siluf(a);
    }
    __syncthreads();
    if (t < 64) {
        float a = 0.f;
        for (int c = 0; c < 128; ++c) a += xr0[c] * Wso2[c * 64 + t];
        a *= efs[t];
        msg0[t] = a * sigmf(a);
    }
    __syncthreads();
    {
        float a = 0.f;
        for (int d = 0; d < 64; ++d) a += msg0[d] * Wa[d * 128 + t];
        float av = (a > 0.f) ? a : 0.2f * a;
        ared[t] = av * va[t];
    }
    __syncthreads();
    if (t < NH) {
        float sum = 0.f;
        for (int a = 0; a < 32; ++a) sum += ared[t * 32 + a];
        logits[(size_t)e * NH + t] = sum;
    }
}

// ---- CSR build ----
__global__ void k_count(const int* __restrict__ receivers, int* __restrict__ counts, int E) {
    int e = blockIdx.x * blockDim.x + threadIdx.x;
    if (e < E) atomicAdd(&counts[receivers[e]], 1);
}

__global__ void k_scan(int* __restrict__ counts, int* __restrict__ offsets, int n) {
    __shared__ int buf[256];
    __shared__ int base_s;
    int t = threadIdx.x;
    if (t == 0) base_s = 0;
    __syncthreads();
    for (int start = 0; start < n; start += 256) {
        int idx = start + t;
        int v = (idx < n) ? counts[idx] : 0;
        buf[t] = v; __syncthreads();
        for (int o = 1; o < 256; o <<= 1) {
            int x = (t >= o) ? buf[t - o] : 0;
            __syncthreads();
            buf[t] += x;
            __syncthreads();
        }
        int incl = buf[t];
        int b = base_s;
        if (idx < n) { offsets[idx] = b + incl - v; counts[idx] = 0; }
        __syncthreads();
        if (t == 0) base_s = b + buf[255];
        __syncthreads();
    }
    if (t == 0) offsets[n] = base_s;
}

__global__ void k_fill(const int* __restrict__ receivers, const int* __restrict__ offsets,
                       int* __restrict__ cursors, int* __restrict__ edge_ids, int E) {
    int e = blockIdx.x * blockDim.x + threadIdx.x;
    if (e >= E) return;
    int r = receivers[e];
    int pos = atomicAdd(&cursors[r], 1);
    edge_ids[offsets[r] + pos] = e;
}

// ---- k_alpha: per-(node,head) softmax over incoming edges, alpha written
//      IN PLACE over logits (each edge has exactly one receiver -> no conflicts)
__global__ void k_alpha(float* __restrict__ logits, const int* __restrict__ offsets,
                        const int* __restrict__ edge_ids, int N) {
    int i = blockIdx.x * blockDim.x + threadIdx.x;
    if (i >= N * NH) return;
    int n = i >> 2, h = i & 3;
    int o0 = offsets[n], o1 = offsets[n + 1];
    float m = -1e30f;
    for (int j = o0; j < o1; ++j)
        m = fmaxf(m, logits[(size_t)edge_ids[j] * NH + h]);
    float s = 0.f;
    for (int j = o0; j < o1; ++j)
        s += expf(logits[(size_t)edge_ids[j] * NH + h] - m);
    float inv = 1.0f / (s + 1e-9f);
    for (int j = o0; j < o1; ++j) {
        size_t idx = (size_t)edge_ids[j] * NH + h;
        logits[idx] = expf(logits[idx] - m) * inv;
    }
}

// ---- k_tr_fg: transpose from_grid [K][G] -> [G][K] for contiguous uniform rows ----
__global__ void k_tr_fg(const float* __restrict__ from_grid, float* __restrict__ fgT) {
    int i = blockIdx.x * blockDim.x + threadIdx.x;
    if (i < GG * KK) {
        int g = i / KK, k = i - g * KK;
        fgT[g * KK + k] = from_grid[k * GG + g];
    }
}

// ---- k_edge: one WAVE per edge, zero LDS, zero barriers ----
// lane = channel (64). Per-lane data in regs; wave-uniform operands via s_load;
// transposes over the lane dim via v_readlane (VALU pipe, not LDS).
__global__ __launch_bounds__(256) void k_edge(
        const float* __restrict__ xf, const float* __restrict__ wigner,
        const float* __restrict__ wigner_inv, const float* __restrict__ edist,
        const float* __restrict__ emb_s, const float* __restrict__ emb_r,
        const float* __restrict__ We1, const float* __restrict__ We2,
        const float* __restrict__ Wso2, const float* __restrict__ Wv,
        const float* __restrict__ Wo, const float* __restrict__ g1,
        const float* __restrict__ scale, const float* __restrict__ alpha,
        const int* __restrict__ species, const int* __restrict__ senders,
        const int* __restrict__ receivers, float* __restrict__ out, int E) {
    const int lane = threadIdx.x & 63;
    const int e = __builtin_amdgcn_readfirstlane(blockIdx.x * 4 + (threadIdx.x >> 6));
    if (e >= E) return;
    const int s = senders[e];
    const int r = receivers[e];
    const float scs = scale[s], scr = scale[r];

    float g1l[5];
#pragma unroll
    for (int l = 0; l < 5; ++l) g1l[l] = g1[l * 64 + lane];

    // normed sender (xs) / receiver (xc) features, lane = channel
    float xs[25], xc[25];
#pragma unroll
    for (int k = 0; k < 25; ++k) {
        const float gk = g1l[lpk(k)];
        xs[k] = xf[(size_t)s * 1600 + k * 64 + lane] * scs * gk;
        xc[k] = xf[(size_t)r * 1600 + k * 64 + lane] * scr * gk;
    }

    // xr = wigner @ [xs | xc]  (wigner rows wave-uniform -> SGPR operand FMAs)
    const float* __restrict__ wge = wigner + (size_t)e * 475;
    float xrs[19], xrc[19];
#pragma unroll
    for (int rr = 0; rr < 19; ++rr) {
        float a = 0.f, b = 0.f;
#pragma unroll
        for (int k = 0; k < 25; ++k) {
            const float w = wge[rr * 25 + k];
            a += w * xs[k];
            b += w * xc[k];
        }
        xrs[rr] = a; xrc[rr] = b;
    }

    // invariant edge MLP: h1 = silu(efin @ We1); efs = silu(h1 @ We2)
    float h1a = 0.f, h1b = 0.f;
    {
        const float* __restrict__ eda = edist + (size_t)e * 64;
        const float* __restrict__ esa = emb_s + (size_t)species[s] * 32;
        const float* __restrict__ era = emb_r + (size_t)species[r] * 32;
        for (int c = 0; c < 64; ++c) {
            const float v = eda[c];
            h1a += v * We1[c * 128 + lane];
            h1b += v * We1[c * 128 + 64 + lane];
        }
        for (int c = 0; c < 32; ++c) {
            const float v = esa[c];
            h1a += v * We1[(64 + c) * 128 + lane];
            h1b += v * We1[(64 + c) * 128 + 64 + lane];
        }
        for (int c = 0; c < 32; ++c) {
            const float v = era[c];
            h1a += v * We1[(96 + c) * 128 + lane];
            h1b += v * We1[(96 + c) * 128 + 64 + lane];
        }
        h1a = siluf(h1a); h1b = siluf(h1b);
    }
    float efs = 0.f;
    for (int j = 0; j < 64; ++j) {
        efs += rdlane(h1a, j) * We2[j * 64 + lane];
        efs += rdlane(h1b, j) * We2[(j + 64) * 64 + lane];
    }
    efs = siluf(efs);

    // msg = (xr @ Wso2) * efs, then S2 gate with sigmoid of row 0
    float msg[19];
#pragma unroll
    for (int rr = 0; rr < 19; ++rr) msg[rr] = 0.f;
    for (int c = 0; c < 64; ++c) {
        const float w0 = Wso2[c * 64 + lane];
        const float w1 = Wso2[(64 + c) * 64 + lane];
#pragma unroll
        for (int rr = 0; rr < 19; ++rr)
            msg[rr] += rdlane(xrs[rr], c) * w0 + rdlane(xrc[rr], c) * w1;
    }
#pragma unroll
    for (int rr = 0; rr < 19; ++rr) msg[rr] *= efs;
    const float gate = sigmf(msg[0]);
#pragma unroll
    for (int rr = 0; rr < 19; ++rr) msg[rr] *= gate;

    // attention weight for this lane's head group (VC=16 -> h = lane>>4)
    const int hh = lane >> 4;
    const float al = alpha[(size_t)e * NH + hh];

    // v2 = (msg @ Wv) * alpha
    float v2[19];
#pragma unroll
    for (int rr = 0; rr < 19; ++rr) v2[rr] = 0.f;
    for (int d = 0; d < 64; ++d) {
        const float w = Wv[d * 64 + lane];
#pragma unroll
        for (int rr = 0; rr < 19; ++rr) v2[rr] += rdlane(msg[rr], d) * w;
    }
#pragma unroll
    for (int rr = 0; rr < 19; ++rr) v2[rr] *= al;

    // z = v2 @ Wo  (reassociated: expand 19 -> 25 rows LAST)
    float z[19];
#pragma unroll
    for (int rr = 0; rr < 19; ++rr) z[rr] = 0.f;
    for (int d = 0; d < 64; ++d) {
        const float w = Wo[d * 64 + lane];
#pragma unroll
        for (int rr = 0; rr < 19; ++rr) z[rr] += rdlane(v2[rr], d) * w;
    }

    // out[r] += wigner_inv @ z  (pure SGPR x VGPR FMAs + coalesced atomics)
    const float* __restrict__ wvi = wigner_inv + (size_t)e * 475;
    float* __restrict__ op = out + (size_t)r * 1600;
#pragma unroll
    for (int k = 0; k < 25; ++k) {
        float a = 0.f;
#pragma unroll
        for (int rr = 0; rr < 19; ++rr) a += wvi[k * 19 + rr] * z[rr];
        atomicAdd(&op[k * 64 + lane], a);
    }
}

// ---- k_ffn: one WAVE per node: residual + norm2 + S2-grid FFN, zero LDS ----
// Factorized: Y = xn @ Wf1 (once per node), h[g] = silu(tg . Y) pure-FMA,
// U = sum_g fg * h (lane=j), racc = U @ Wf2 (single transpose of U).
__global__ __launch_bounds__(256) void k_ffn(
        const float* __restrict__ xf, const float* __restrict__ g2,
        const float* __restrict__ to_grid, const float* __restrict__ fgT,
        const float* __restrict__ Wf1, const float* __restrict__ Wf2,
        float* __restrict__ out, int N) {
    const int lane = threadIdx.x & 63;
    const int n = __builtin_amdgcn_readfirstlane(blockIdx.x * 4 + (threadIdx.x >> 6));
    if (n >= N) return;
    const float* __restrict__ oin = out + (size_t)n * 1600;
    const float* __restrict__ xin = xf + (size_t)n * 1600;

    // X = attn_out + residual ; rms over all 1600
    float xn[25];
    float ss = 0.f;
#pragma unroll
    for (int k = 0; k < 25; ++k) {
        const float X = oin[k * 64 + lane] + xin[k * 64 + lane];
        xn[k] = X;
        ss += X * X;
    }
#pragma unroll
    for (int m = 1; m < 64; m <<= 1) ss += __shfl_xor(ss, m, 64);
    const float sc2 = rsqrtf(ss * (1.0f / 1600.f) + 1e-6f);
#pragma unroll
    for (int k = 0; k < 25; ++k) xn[k] *= sc2 * g2[lpk(k) * 64 + lane];

    // Y[k][j] = sum_c xn[k][c] * Wf1[c][j]   (lane=j, halves j=lane / j=64+lane)
    float Ya[25], Yb[25];
#pragma unroll
    for (int k = 0; k < 25; ++k) { Ya[k] = 0.f; Yb[k] = 0.f; }
    for (int c = 0; c < 64; ++c) {
        const float w0 = Wf1[c * FFH + lane];
        const float w1 = Wf1[c * FFH + 64 + lane];
#pragma unroll
        for (int k = 0; k < 25; ++k) {
            const float sv = rdlane(xn[k], c);
            Ya[k] += sv * w0;
            Yb[k] += sv * w1;
        }
    }

    // g-loop: h[g][j] = silu(sum_k tg[g][k]*Y[k][j]);  U[k][j] += fg[g][k]*h[g][j]
    float Ua[25], Ub[25];
#pragma unroll
    for (int k = 0; k < 25; ++k) { Ua[k] = 0.f; Ub[k] = 0.f; }
#pragma unroll 2
    for (int g = 0; g < GG; ++g) {
        const float* __restrict__ tg = to_grid + (size_t)g * KK;
        const float* __restrict__ fg = fgT + (size_t)g * KK;
        float ha = 0.f, hb = 0.f;
#pragma unroll
        for (int k = 0; k < 25; ++k) {
            const float t = tg[k];
            ha += t * Ya[k];
            hb += t * Yb[k];
        }
        ha = siluf(ha); hb = siluf(hb);
#pragma unroll
        for (int k = 0; k < 25; ++k) {
            const float f = fg[k];
            Ua[k] += f * ha;
            Ub[k] += f * hb;
        }
    }

    // racc[k][c] = sum_j U[k][j] * Wf2[j][c]   (lane=c; single U transpose)
    float racc[25];
#pragma unroll
    for (int k = 0; k < 25; ++k) racc[k] = 0.f;
    for (int j = 0; j < 64; ++j) {
        const float w0 = Wf2[j * 64 + lane];
        const float w1 = Wf2[(64 + j) * 64 + lane];
#pragma unroll
        for (int k = 0; k < 25; ++k)
            racc[k] += rdlane(Ua[k], j) * w0 + rdlane(Ub[k], j) * w1;
    }

    float* __restrict__ op = out + (size_t)n * 1600;
#pragma unroll
    for (int k = 0; k < 25; ++k)
        op[k * 64 + lane] = oin[k * 64 + lane] + xin[k * 64 + lane] + racc[k];
}

extern "C" void kernel_launch(void* const* d_in, const int* in_sizes, int n_in,
                              void* d_out, int out_size, void* d_ws, size_t ws_size,
                              hipStream_t stream) {
    const float* node_feats     = (const float*)d_in[0];
    const float* edge_distances = (const float*)d_in[1];
    const float* wigner         = (const float*)d_in[2];
    const float* wigner_inv     = (const float*)d_in[3];
    const int*   node_species   = (const int*)  d_in[4];
    const int*   senders        = (const int*)  d_in[5];
    const int*   receivers      = (const int*)  d_in[6];
    const float* g1             = (const float*)d_in[7];
    const float* g2             = (const float*)d_in[8];
    const float* emb_s          = (const float*)d_in[9];
    const float* emb_r          = (const float*)d_in[10];
    const float* We1            = (const float*)d_in[11];
    const float* We2            = (const float*)d_in[12];
    const float* Wso2           = (const float*)d_in[13];
    const float* Wa             = (const float*)d_in[14];
    const float* va             = (const float*)d_in[15];
    const float* Wv             = (const float*)d_in[16];
    const float* Wo             = (const float*)d_in[17];
    const float* to_grid        = (const float*)d_in[18];
    const float* from_grid      = (const float*)d_in[19];
    const float* Wf1            = (const float*)d_in[20];
    const float* Wf2            = (const float*)d_in[21];

    const int N = in_sizes[4];
    const int E = in_sizes[5];

    char* ws = (char*)d_ws;
    size_t o = 0;
    float* scale    = (float*)(ws + o); o += (size_t)N * 4;
    int*   counts   = (int*)  (ws + o); o += (size_t)N * 4;
    int*   offsets  = (int*)  (ws + o); o += (size_t)(N + 1) * 4;
    int*   edge_ids = (int*)  (ws + o); o += (size_t)E * 4;
    float* logits   = (float*)(ws + o); o += (size_t)E * NH * 4;
    float* fgT      = (float*)(ws + o); o += (size_t)GG * KK * 4;
    // total ws use ~730 KB

    hipMemsetAsync(counts, 0, (size_t)N * 4, stream);
    hipMemsetAsync(d_out, 0, (size_t)N * 1600 * 4, stream);

    k_scale<<<N, 256, 0, stream>>>(node_feats, scale);
    k_edge_logits<<<E, 128, 0, stream>>>(edge_distances, emb_s, emb_r, We1, We2, Wso2,
                                         Wa, va, wigner, node_feats, g1, scale,
                                         node_species, senders, receivers, logits);
    k_count<<<(E + 255) / 256, 256, 0, stream>>>(receivers, counts, E);
    k_scan<<<1, 256, 0, stream>>>(counts, offsets, N);
    k_fill<<<(E + 255) / 256, 256, 0, stream>>>(receivers, offsets, counts, edge_ids, E);
    k_alpha<<<(N * NH + 255) / 256, 256, 0, stream>>>(logits, offsets, edge_ids, N);
    k_tr_fg<<<(GG * KK + 255) / 256, 256, 0, stream>>>(from_grid, fgT);
    k_edge<<<(E + 3) / 4, 256, 0, stream>>>(node_feats, wigner, wigner_inv,
                                            edge_distances, emb_s, emb_r, We1, We2,
                                            Wso2, Wv, Wo, g1, scale, logits,
                                            node_species, senders, receivers,
                                            (float*)d_out, E);
    k_ffn<<<(N + 3) / 4, 256, 0, stream>>>(node_feats, g2, to_grid, fgT, Wf1, Wf2,
                                           (float*)d_out, N);
}

// Round 4
// 1427.466 us; speedup vs baseline: 4.5993x; 1.3622x over previous
//
#include <hip/hip_runtime.h>

#define KK 25
#define KRR 19
#define NH 4
#define GG 100
#define FFH 128

__device__ __constant__ int c_l_per_k[25] = {0, 1,1,1, 2,2,2,2,2,
                                             3,3,3,3,3,3,3,
                                             4,4,4,4,4,4,4,4,4};

__device__ __forceinline__ float siluf(float x) { return x / (1.0f + __expf(-x)); }
__device__ __forceinline__ float sigmf(float x) { return 1.0f / (1.0f + __expf(-x)); }

// compile-time l(k) for fully-unrolled loops
__device__ __forceinline__ constexpr int lpk(int k) {
    return (k == 0) ? 0 : (k < 4) ? 1 : (k < 9) ? 2 : (k < 16) ? 3 : 4;
}

// cross-lane extract on the VALU pipe (not LDS): v_readlane_b32
__device__ __forceinline__ float rdlane(float x, int l) {
    return __int_as_float(__builtin_amdgcn_readlane(__float_as_int(x), l));
}

// ---- k_scale: per-node RMS scale (f32) ----
__global__ void k_scale(const float* __restrict__ xf, float* __restrict__ scale) {
    int n = blockIdx.x, t = threadIdx.x;
    __shared__ float red[256];
    const float* xp = xf + (size_t)n * 1600;
    float ss = 0.f;
    for (int i = t; i < 1600; i += 256) { float v = xp[i]; ss += v * v; }
    red[t] = ss; __syncthreads();
    for (int s = 128; s > 0; s >>= 1) { if (t < s) red[t] += red[t + s]; __syncthreads(); }
    if (t == 0) scale[n] = rsqrtf(red[0] / 1600.0f + 1e-6f);
}

// ---- k_pq: per-node P = xnorm @ Wso2_top, Q = xnorm @ Wso2_bot ----
// one wave per node, lane = d (SO2 hidden channel)
__global__ __launch_bounds__(256) void k_pq(
        const float* __restrict__ xf, const float* __restrict__ g1,
        const float* __restrict__ scale, const float* __restrict__ Wso2,
        float* __restrict__ pq, int N) {
    const int lane = threadIdx.x & 63;
    const int n = __builtin_amdgcn_readfirstlane(blockIdx.x * 4 + (threadIdx.x >> 6));
    if (n >= N) return;
    const float sc = scale[n];
    float xn[25];
#pragma unroll
    for (int k = 0; k < 25; ++k)
        xn[k] = xf[(size_t)n * 1600 + k * 64 + lane] * sc * g1[lpk(k) * 64 + lane];
    float P[25], Q[25];
#pragma unroll
    for (int k = 0; k < 25; ++k) { P[k] = 0.f; Q[k] = 0.f; }
    for (int c = 0; c < 64; ++c) {
        const float w0 = Wso2[c * 64 + lane];
        const float w1 = Wso2[(64 + c) * 64 + lane];
#pragma unroll
        for (int k = 0; k < 25; ++k) {
            const float sv = rdlane(xn[k], c);
            P[k] += sv * w0;
            Q[k] += sv * w1;
        }
    }
    float* __restrict__ pp = pq + (size_t)n * 1600;
    float* __restrict__ qp = pq + (size_t)N * 1600 + (size_t)n * 1600;
#pragma unroll
    for (int k = 0; k < 25; ++k) {
        pp[k * 64 + lane] = P[k];
        qp[k * 64 + lane] = Q[k];
    }
}

// ---- k_wvo: Wvo[h] = Wv[:, h*16:(h+1)*16] @ Wo[h*16:(h+1)*16, :] ----
__global__ void k_wvo(const float* __restrict__ Wv, const float* __restrict__ Wo,
                      float* __restrict__ Wvo) {
    int i = blockIdx.x * blockDim.x + threadIdx.x;
    if (i >= 4 * 64 * 64) return;
    int h = i >> 12, d = (i >> 6) & 63, d3 = i & 63;
    float a = 0.f;
    for (int vc = 0; vc < 16; ++vc)
        a += Wv[d * 64 + h * 16 + vc] * Wo[(h * 16 + vc) * 64 + d3];
    Wvo[i] = a;
}

// ---- k_edge_logits: edge MLP + attention logits (normed x on the fly) ----
// also persists efs to workspace for k_edge_fast (if efsbuf != nullptr)
__global__ __launch_bounds__(128) void k_edge_logits(
        const float* __restrict__ edist, const float* __restrict__ emb_s,
        const float* __restrict__ emb_r, const float* __restrict__ We1,
        const float* __restrict__ We2, const float* __restrict__ Wso2,
        const float* __restrict__ Wa, const float* __restrict__ va,
        const float* __restrict__ wigner, const float* __restrict__ xf,
        const float* __restrict__ g1, const float* __restrict__ scale,
        const int* __restrict__ species, const int* __restrict__ senders,
        const int* __restrict__ receivers, float* __restrict__ logits,
        float* __restrict__ efsbuf) {
    int e = blockIdx.x, t = threadIdx.x;
    __shared__ float efin[128], h1[128], efs[64], xr0[128], msg0[64], ared[128];
    int s = senders[e], r = receivers[e];
    if (t < 64)       efin[t] = edist[(size_t)e * 64 + t];
    else if (t < 96)  efin[t] = emb_s[species[s] * 32 + (t - 64)];
    else              efin[t] = emb_r[species[r] * 32 + (t - 96)];
    {   // xr row 0 on the fly
        int c = t & 63;
        int node = (t < 64) ? s : r;
        float sc = scale[node];
        const float* xb = xf + (size_t)node * 1600;
        float a = 0.f;
        for (int k = 0; k < KK; ++k)
            a += wigner[(size_t)e * 475 + k] * xb[k * 64 + c] * g1[c_l_per_k[k] * 64 + c];
        xr0[t] = a * sc;
    }
    __syncthreads();
    {
        float a = 0.f;
        for (int c = 0; c < 128; ++c) a += efin[c] * We1[c * 128 + t];
        h1[t] = siluf(a);
    }
    __syncthreads();
    if (t < 64) {
        float a = 0.f;
        for (int c = 0; c < 128; ++c) a += h1[c] * We2[c * 64 + t];
        float ef = siluf(a);
        efs[t] = ef;
        if (efsbuf) efsbuf[(size_t)e * 64 + t] = ef;
    }
    __syncthreads();
    if (t < 64) {
        float a = 0.f;
        for (int c = 0; c < 128; ++c) a += xr0[c] * Wso2[c * 64 + t];
        a *= efs[t];
        msg0[t] = a * sigmf(a);
    }
    __syncthreads();
    {
        float a = 0.f;
        for (int d = 0; d < 64; ++d) a += msg0[d] * Wa[d * 128 + t];
        float av = (a > 0.f) ? a : 0.2f * a;
        ared[t] = av * va[t];
    }
    __syncthreads();
    if (t < NH) {
        float sum = 0.f;
        for (int a = 0; a < 32; ++a) sum += ared[t * 32 + a];
        logits[(size_t)e * NH + t] = sum;
    }
}

// ---- CSR build ----
__global__ void k_count(const int* __restrict__ receivers, int* __restrict__ counts, int E) {
    int e = blockIdx.x * blockDim.x + threadIdx.x;
    if (e < E) atomicAdd(&counts[receivers[e]], 1);
}

__global__ void k_scan(int* __restrict__ counts, int* __restrict__ offsets, int n) {
    __shared__ int buf[256];
    __shared__ int base_s;
    int t = threadIdx.x;
    if (t == 0) base_s = 0;
    __syncthreads();
    for (int start = 0; start < n; start += 256) {
        int idx = start + t;
        int v = (idx < n) ? counts[idx] : 0;
        buf[t] = v; __syncthreads();
        for (int o = 1; o < 256; o <<= 1) {
            int x = (t >= o) ? buf[t - o] : 0;
            __syncthreads();
            buf[t] += x;
            __syncthreads();
        }
        int incl = buf[t];
        int b = base_s;
        if (idx < n) { offsets[idx] = b + incl - v; counts[idx] = 0; }
        __syncthreads();
        if (t == 0) base_s = b + buf[255];
        __syncthreads();
    }
    if (t == 0) offsets[n] = base_s;
}

__global__ void k_fill(const int* __restrict__ receivers, const int* __restrict__ offsets,
                       int* __restrict__ cursors, int* __restrict__ edge_ids, int E) {
    int e = blockIdx.x * blockDim.x + threadIdx.x;
    if (e >= E) return;
    int r = receivers[e];
    int pos = atomicAdd(&cursors[r], 1);
    edge_ids[offsets[r] + pos] = e;
}

// ---- k_alpha: per-(node,head) softmax over incoming edges, alpha written
//      IN PLACE over logits (each edge has exactly one receiver -> no conflicts)
__global__ void k_alpha(float* __restrict__ logits, const int* __restrict__ offsets,
                        const int* __restrict__ edge_ids, int N) {
    int i = blockIdx.x * blockDim.x + threadIdx.x;
    if (i >= N * NH) return;
    int n = i >> 2, h = i & 3;
    int o0 = offsets[n], o1 = offsets[n + 1];
    float m = -1e30f;
    for (int j = o0; j < o1; ++j)
        m = fmaxf(m, logits[(size_t)edge_ids[j] * NH + h]);
    float s = 0.f;
    for (int j = o0; j < o1; ++j)
        s += expf(logits[(size_t)edge_ids[j] * NH + h] - m);
    float inv = 1.0f / (s + 1e-9f);
    for (int j = o0; j < o1; ++j) {
        size_t idx = (size_t)edge_ids[j] * NH + h;
        logits[idx] = expf(logits[idx] - m) * inv;
    }
}

// ---- k_tr_fg: transpose from_grid [K][G] -> [G][K] for contiguous uniform rows ----
__global__ void k_tr_fg(const float* __restrict__ from_grid, float* __restrict__ fgT) {
    int i = blockIdx.x * blockDim.x + threadIdx.x;
    if (i < GG * KK) {
        int g = i / KK, k = i - g * KK;
        fgT[g * KK + k] = from_grid[k * GG + g];
    }
}

// ---- k_edge_fast: one WAVE per edge using precomputed P/Q, Wvo, efs ----
// msg_pre = wig @ (P[s]+Q[r]); z = sum_d eg_d*msg_pre[:,d]*(sum_h alpha_h Wvo_h[d,:]);
// out[r] += winv @ z
__global__ __launch_bounds__(256) void k_edge_fast(
        const float* __restrict__ pq, const float* __restrict__ wigner,
        const float* __restrict__ wigner_inv, const float* __restrict__ Wvo,
        const float* __restrict__ efsbuf, const float* __restrict__ alpha,
        const int* __restrict__ senders, const int* __restrict__ receivers,
        float* __restrict__ out, int N, int E) {
    const int lane = threadIdx.x & 63;
    const int e = __builtin_amdgcn_readfirstlane(blockIdx.x * 4 + (threadIdx.x >> 6));
    if (e >= E) return;
    const int s = senders[e];
    const int r = receivers[e];

    // XW[k][d] = P[s][k][d] + Q[r][k][d]   (lane = d)
    const float* __restrict__ Ps = pq + (size_t)s * 1600;
    const float* __restrict__ Qr = pq + (size_t)N * 1600 + (size_t)r * 1600;
    float XW[25];
#pragma unroll
    for (int k = 0; k < 25; ++k) XW[k] = Ps[k * 64 + lane] + Qr[k * 64 + lane];

    // msg_pre[rr][d] = sum_k wig[rr][k] * XW[k][d]  (wigner rows -> SGPR FMAs)
    const float* __restrict__ wge = wigner + (size_t)e * 475;
    float mp[19];
#pragma unroll
    for (int rr = 0; rr < 19; ++rr) {
        float a = 0.f;
#pragma unroll
        for (int k = 0; k < 25; ++k) a += wge[rr * 25 + k] * XW[k];
        mp[rr] = a;
    }

    // eg[d] = efs[d] * sigmoid(msg_pre[0][d]*efs[d])   (lane = d)
    const float ef = efsbuf[(size_t)e * 64 + lane];
    const float eg = ef * sigmf(mp[0] * ef);

    const float a0 = alpha[(size_t)e * NH + 0];
    const float a1 = alpha[(size_t)e * NH + 1];
    const float a2 = alpha[(size_t)e * NH + 2];
    const float a3 = alpha[(size_t)e * NH + 3];

    // z[rr][d3] = sum_d (mp[rr][d]*eg[d]) * (sum_h alpha_h * Wvo_h[d][d3])
    float z[19];
#pragma unroll
    for (int rr = 0; rr < 19; ++rr) z[rr] = 0.f;
    for (int d = 0; d < 64; ++d) {
        float wv = a0 * Wvo[d * 64 + lane]
                 + a1 * Wvo[4096 + d * 64 + lane]
                 + a2 * Wvo[8192 + d * 64 + lane]
                 + a3 * Wvo[12288 + d * 64 + lane];
        wv *= rdlane(eg, d);
#pragma unroll
        for (int rr = 0; rr < 19; ++rr) z[rr] += rdlane(mp[rr], d) * wv;
    }

    // out[r] += wigner_inv @ z
    const float* __restrict__ wvi = wigner_inv + (size_t)e * 475;
    float* __restrict__ op = out + (size_t)r * 1600;
#pragma unroll
    for (int k = 0; k < 25; ++k) {
        float a = 0.f;
#pragma unroll
        for (int rr = 0; rr < 19; ++rr) a += wvi[k * 19 + rr] * z[rr];
        atomicAdd(&op[k * 64 + lane], a);
    }
}

// ---- k_edge (fallback, round-3 verified): one WAVE per edge, zero LDS ----
__global__ __launch_bounds__(256) void k_edge(
        const float* __restrict__ xf, const float* __restrict__ wigner,
        const float* __restrict__ wigner_inv, const float* __restrict__ edist,
        const float* __restrict__ emb_s, const float* __restrict__ emb_r,
        const float* __restrict__ We1, const float* __restrict__ We2,
        const float* __restrict__ Wso2, const float* __restrict__ Wv,
        const float* __restrict__ Wo, const float* __restrict__ g1,
        const float* __restrict__ scale, const float* __restrict__ alpha,
        const int* __restrict__ species, const int* __restrict__ senders,
        const int* __restrict__ receivers, float* __restrict__ out, int E) {
    const int lane = threadIdx.x & 63;
    const int e = __builtin_amdgcn_readfirstlane(blockIdx.x * 4 + (threadIdx.x >> 6));
    if (e >= E) return;
    const int s = senders[e];
    const int r = receivers[e];
    const float scs = scale[s], scr = scale[r];

    float g1l[5];
#pragma unroll
    for (int l = 0; l < 5; ++l) g1l[l] = g1[l * 64 + lane];

    float xs[25], xc[25];
#pragma unroll
    for (int k = 0; k < 25; ++k) {
        const float gk = g1l[lpk(k)];
        xs[k] = xf[(size_t)s * 1600 + k * 64 + lane] * scs * gk;
        xc[k] = xf[(size_t)r * 1600 + k * 64 + lane] * scr * gk;
    }

    const float* __restrict__ wge = wigner + (size_t)e * 475;
    float xrs[19], xrc[19];
#pragma unroll
    for (int rr = 0; rr < 19; ++rr) {
        float a = 0.f, b = 0.f;
#pragma unroll
        for (int k = 0; k < 25; ++k) {
            const float w = wge[rr * 25 + k];
            a += w * xs[k];
            b += w * xc[k];
        }
        xrs[rr] = a; xrc[rr] = b;
    }

    float h1a = 0.f, h1b = 0.f;
    {
        const float* __restrict__ eda = edist + (size_t)e * 64;
        const float* __restrict__ esa = emb_s + (size_t)species[s] * 32;
        const float* __restrict__ era = emb_r + (size_t)species[r] * 32;
        for (int c = 0; c < 64; ++c) {
            const float v = eda[c];
            h1a += v * We1[c * 128 + lane];
            h1b += v * We1[c * 128 + 64 + lane];
        }
        for (int c = 0; c < 32; ++c) {
            const float v = esa[c];
            h1a += v * We1[(64 + c) * 128 + lane];
            h1b += v * We1[(64 + c) * 128 + 64 + lane];
        }
        for (int c = 0; c < 32; ++c) {
            const float v = era[c];
            h1a += v * We1[(96 + c) * 128 + lane];
            h1b += v * We1[(96 + c) * 128 + 64 + lane];
        }
        h1a = siluf(h1a); h1b = siluf(h1b);
    }
    float efs = 0.f;
    for (int j = 0; j < 64; ++j) {
        efs += rdlane(h1a, j) * We2[j * 64 + lane];
        efs += rdlane(h1b, j) * We2[(j + 64) * 64 + lane];
    }
    efs = siluf(efs);

    float msg[19];
#pragma unroll
    for (int rr = 0; rr < 19; ++rr) msg[rr] = 0.f;
    for (int c = 0; c < 64; ++c) {
        const float w0 = Wso2[c * 64 + lane];
        const float w1 = Wso2[(64 + c) * 64 + lane];
#pragma unroll
        for (int rr = 0; rr < 19; ++rr)
            msg[rr] += rdlane(xrs[rr], c) * w0 + rdlane(xrc[rr], c) * w1;
    }
#pragma unroll
    for (int rr = 0; rr < 19; ++rr) msg[rr] *= efs;
    const float gate = sigmf(msg[0]);
#pragma unroll
    for (int rr = 0; rr < 19; ++rr) msg[rr] *= gate;

    const int hh = lane >> 4;
    const float al = alpha[(size_t)e * NH + hh];

    float v2[19];
#pragma unroll
    for (int rr = 0; rr < 19; ++rr) v2[rr] = 0.f;
    for (int d = 0; d < 64; ++d) {
        const float w = Wv[d * 64 + lane];
#pragma unroll
        for (int rr = 0; rr < 19; ++rr) v2[rr] += rdlane(msg[rr], d) * w;
    }
#pragma unroll
    for (int rr = 0; rr < 19; ++rr) v2[rr] *= al;

    float z[19];
#pragma unroll
    for (int rr = 0; rr < 19; ++rr) z[rr] = 0.f;
    for (int d = 0; d < 64; ++d) {
        const float w = Wo[d * 64 + lane];
#pragma unroll
        for (int rr = 0; rr < 19; ++rr) z[rr] += rdlane(v2[rr], d) * w;
    }

    const float* __restrict__ wvi = wigner_inv + (size_t)e * 475;
    float* __restrict__ op = out + (size_t)r * 1600;
#pragma unroll
    for (int k = 0; k < 25; ++k) {
        float a = 0.f;
#pragma unroll
        for (int rr = 0; rr < 19; ++rr) a += wvi[k * 19 + rr] * z[rr];
        atomicAdd(&op[k * 64 + lane], a);
    }
}

// ---- k_ffn: one WAVE per node: residual + norm2 + S2-grid FFN, zero LDS ----
// Factorized: Y = xn @ Wf1 (once per node), h[g] = silu(tg . Y) pure-FMA,
// U = sum_g fg * h (lane=j), racc = U @ Wf2 (single transpose of U).
__global__ __launch_bounds__(256) void k_ffn(
        const float* __restrict__ xf, const float* __restrict__ g2,
        const float* __restrict__ to_grid, const float* __restrict__ fgT,
        const float* __restrict__ Wf1, const float* __restrict__ Wf2,
        float* __restrict__ out, int N) {
    const int lane = threadIdx.x & 63;
    const int n = __builtin_amdgcn_readfirstlane(blockIdx.x * 4 + (threadIdx.x >> 6));
    if (n >= N) return;
    const float* __restrict__ oin = out + (size_t)n * 1600;
    const float* __restrict__ xin = xf + (size_t)n * 1600;

    float xn[25];
    float ss = 0.f;
#pragma unroll
    for (int k = 0; k < 25; ++k) {
        const float X = oin[k * 64 + lane] + xin[k * 64 + lane];
        xn[k] = X;
        ss += X * X;
    }
#pragma unroll
    for (int m = 1; m < 64; m <<= 1) ss += __shfl_xor(ss, m, 64);
    const float sc2 = rsqrtf(ss * (1.0f / 1600.f) + 1e-6f);
#pragma unroll
    for (int k = 0; k < 25; ++k) xn[k] *= sc2 * g2[lpk(k) * 64 + lane];

    // Y[k][j] = sum_c xn[k][c] * Wf1[c][j]
    float Ya[25], Yb[25];
#pragma unroll
    for (int k = 0; k < 25; ++k) { Ya[k] = 0.f; Yb[k] = 0.f; }
    for (int c = 0; c < 64; ++c) {
        const float w0 = Wf1[c * FFH + lane];
        const float w1 = Wf1[c * FFH + 64 + lane];
#pragma unroll
        for (int k = 0; k < 25; ++k) {
            const float sv = rdlane(xn[k], c);
            Ya[k] += sv * w0;
            Yb[k] += sv * w1;
        }
    }

    float Ua[25], Ub[25];
#pragma unroll
    for (int k = 0; k < 25; ++k) { Ua[k] = 0.f; Ub[k] = 0.f; }
#pragma unroll 2
    for (int g = 0; g < GG; ++g) {
        const float* __restrict__ tg = to_grid + (size_t)g * KK;
        const float* __restrict__ fg = fgT + (size_t)g * KK;
        float ha = 0.f, hb = 0.f;
#pragma unroll
        for (int k = 0; k < 25; ++k) {
            const float t = tg[k];
            ha += t * Ya[k];
            hb += t * Yb[k];
        }
        ha = siluf(ha); hb = siluf(hb);
#pragma unroll
        for (int k = 0; k < 25; ++k) {
            const float f = fg[k];
            Ua[k] += f * ha;
            Ub[k] += f * hb;
        }
    }

    float racc[25];
#pragma unroll
    for (int k = 0; k < 25; ++k) racc[k] = 0.f;
    for (int j = 0; j < 64; ++j) {
        const float w0 = Wf2[j * 64 + lane];
        const float w1 = Wf2[(64 + j) * 64 + lane];
#pragma unroll
        for (int k = 0; k < 25; ++k)
            racc[k] += rdlane(Ua[k], j) * w0 + rdlane(Ub[k], j) * w1;
    }

    float* __restrict__ op = out + (size_t)n * 1600;
#pragma unroll
    for (int k = 0; k < 25; ++k)
        op[k * 64 + lane] = oin[k * 64 + lane] + xin[k * 64 + lane] + racc[k];
}

extern "C" void kernel_launch(void* const* d_in, const int* in_sizes, int n_in,
                              void* d_out, int out_size, void* d_ws, size_t ws_size,
                              hipStream_t stream) {
    const float* node_feats     = (const float*)d_in[0];
    const float* edge_distances = (const float*)d_in[1];
    const float* wigner         = (const float*)d_in[2];
    const float* wigner_inv     = (const float*)d_in[3];
    const int*   node_species   = (const int*)  d_in[4];
    const int*   senders        = (const int*)  d_in[5];
    const int*   receivers      = (const int*)  d_in[6];
    const float* g1             = (const float*)d_in[7];
    const float* g2             = (const float*)d_in[8];
    const float* emb_s          = (const float*)d_in[9];
    const float* emb_r          = (const float*)d_in[10];
    const float* We1            = (const float*)d_in[11];
    const float* We2            = (const float*)d_in[12];
    const float* Wso2           = (const float*)d_in[13];
    const float* Wa             = (const float*)d_in[14];
    const float* va             = (const float*)d_in[15];
    const float* Wv             = (const float*)d_in[16];
    const float* Wo             = (const float*)d_in[17];
    const float* to_grid        = (const float*)d_in[18];
    const float* from_grid      = (const float*)d_in[19];
    const float* Wf1            = (const float*)d_in[20];
    const float* Wf2            = (const float*)d_in[21];

    const int N = in_sizes[4];
    const int E = in_sizes[5];

    char* ws = (char*)d_ws;
    size_t o = 0;
    float* scale    = (float*)(ws + o); o += (size_t)N * 4;
    int*   counts   = (int*)  (ws + o); o += (size_t)N * 4;
    int*   offsets  = (int*)  (ws + o); o += (size_t)(N + 1) * 4;
    int*   edge_ids = (int*)  (ws + o); o += (size_t)E * 4;
    float* logits   = (float*)(ws + o); o += (size_t)E * NH * 4;
    float* fgT      = (float*)(ws + o); o += (size_t)GG * KK * 4;
    // optional fast-path buffers (gated on ws_size)
    size_t o_fast = o;
    float* efsbuf = (float*)(ws + o_fast); o_fast += (size_t)E * 64 * 4;
    float* Wvo    = (float*)(ws + o_fast); o_fast += (size_t)4 * 64 * 64 * 4;
    float* pq     = (float*)(ws + o_fast); o_fast += (size_t)N * 3200 * 4;
    const bool fast = (ws_size >= o_fast);

    hipMemsetAsync(counts, 0, (size_t)N * 4, stream);
    hipMemsetAsync(d_out, 0, (size_t)N * 1600 * 4, stream);

    k_scale<<<N, 256, 0, stream>>>(node_feats, scale);
    k_edge_logits<<<E, 128, 0, stream>>>(edge_distances, emb_s, emb_r, We1, We2, Wso2,
                                         Wa, va, wigner, node_feats, g1, scale,
                                         node_species, senders, receivers, logits,
                                         fast ? efsbuf : nullptr);
    k_count<<<(E + 255) / 256, 256, 0, stream>>>(receivers, counts, E);
    k_scan<<<1, 256, 0, stream>>>(counts, offsets, N);
    k_fill<<<(E + 255) / 256, 256, 0, stream>>>(receivers, offsets, counts, edge_ids, E);
    k_alpha<<<(N * NH + 255) / 256, 256, 0, stream>>>(logits, offsets, edge_ids, N);
    k_tr_fg<<<(GG * KK + 255) / 256, 256, 0, stream>>>(from_grid, fgT);
    if (fast) {
        k_pq<<<(N + 3) / 4, 256, 0, stream>>>(node_feats, g1, scale, Wso2, pq, N);
        k_wvo<<<64, 256, 0, stream>>>(Wv, Wo, Wvo);
        k_edge_fast<<<(E + 3) / 4, 256, 0, stream>>>(pq, wigner, wigner_inv, Wvo,
                                                     efsbuf, logits, senders, receivers,
                                                     (float*)d_out, N, E);
    } else {
        k_edge<<<(E + 3) / 4, 256, 0, stream>>>(node_feats, wigner, wigner_inv,
                                                edge_distances, emb_s, emb_r, We1, We2,
                                                Wso2, Wv, Wo, g1, scale, logits,
                                                node_species, senders, receivers,
                                                (float*)d_out, E);
    }
    k_ffn<<<(N + 3) / 4, 256, 0, stream>>>(node_feats, g2, to_grid, fgT, Wf1, Wf2,
                                           (float*)d_out, N);
}

// Round 5
// 1401.817 us; speedup vs baseline: 4.6834x; 1.0183x over previous
//
#include <hip/hip_runtime.h>

#define KK 25
#define KRR 19
#define NH 4
#define GG 100
#define FFH 128

__device__ __constant__ int c_l_per_k[25] = {0, 1,1,1, 2,2,2,2,2,
                                             3,3,3,3,3,3,3,
                                             4,4,4,4,4,4,4,4,4};

__device__ __forceinline__ float siluf(float x) { return x / (1.0f + __expf(-x)); }
__device__ __forceinline__ float sigmf(float x) { return 1.0f / (1.0f + __expf(-x)); }

// compile-time l(k) for fully-unrolled loops
__device__ __forceinline__ constexpr int lpk(int k) {
    return (k == 0) ? 0 : (k < 4) ? 1 : (k < 9) ? 2 : (k < 16) ? 3 : 4;
}

// cross-lane extract on the VALU pipe (not LDS): v_readlane_b32
__device__ __forceinline__ float rdlane(float x, int l) {
    return __int_as_float(__builtin_amdgcn_readlane(__float_as_int(x), l));
}

// ---- k_scale: per-node RMS scale (f32) -- fallback path only ----
__global__ void k_scale(const float* __restrict__ xf, float* __restrict__ scale) {
    int n = blockIdx.x, t = threadIdx.x;
    __shared__ float red[256];
    const float* xp = xf + (size_t)n * 1600;
    float ss = 0.f;
    for (int i = t; i < 1600; i += 256) { float v = xp[i]; ss += v * v; }
    red[t] = ss; __syncthreads();
    for (int s = 128; s > 0; s >>= 1) { if (t < s) red[t] += red[t + s]; __syncthreads(); }
    if (t == 0) scale[n] = rsqrtf(red[0] / 1600.0f + 1e-6f);
}

// ---- k_pq: per-node P = xnorm @ Wso2_top, Q = xnorm @ Wso2_bot (rms inline) ----
__global__ __launch_bounds__(256) void k_pq(
        const float* __restrict__ xf, const float* __restrict__ g1,
        const float* __restrict__ Wso2, float* __restrict__ pq, int N) {
    const int lane = threadIdx.x & 63;
    const int n = __builtin_amdgcn_readfirstlane(blockIdx.x * 4 + (threadIdx.x >> 6));
    if (n >= N) return;
    float xn[25];
    float ss = 0.f;
#pragma unroll
    for (int k = 0; k < 25; ++k) {
        const float v = xf[(size_t)n * 1600 + k * 64 + lane];
        xn[k] = v;
        ss += v * v;
    }
#pragma unroll
    for (int m = 1; m < 64; m <<= 1) ss += __shfl_xor(ss, m, 64);
    const float sc = rsqrtf(ss * (1.0f / 1600.f) + 1e-6f);
#pragma unroll
    for (int k = 0; k < 25; ++k) xn[k] *= sc * g1[lpk(k) * 64 + lane];
    float P[25], Q[25];
#pragma unroll
    for (int k = 0; k < 25; ++k) { P[k] = 0.f; Q[k] = 0.f; }
    for (int c = 0; c < 64; ++c) {
        const float w0 = Wso2[c * 64 + lane];
        const float w1 = Wso2[(64 + c) * 64 + lane];
#pragma unroll
        for (int k = 0; k < 25; ++k) {
            const float sv = rdlane(xn[k], c);
            P[k] += sv * w0;
            Q[k] += sv * w1;
        }
    }
    float* __restrict__ pp = pq + (size_t)n * 1600;
    float* __restrict__ qp = pq + (size_t)N * 1600 + (size_t)n * 1600;
#pragma unroll
    for (int k = 0; k < 25; ++k) {
        pp[k * 64 + lane] = P[k];
        qp[k * 64 + lane] = Q[k];
    }
}

// ---- k_wvo: Wvo[h] = Wv[:, h*16:(h+1)*16] @ Wo[h*16:(h+1)*16, :] ----
__global__ void k_wvo(const float* __restrict__ Wv, const float* __restrict__ Wo,
                      float* __restrict__ Wvo) {
    int i = blockIdx.x * blockDim.x + threadIdx.x;
    if (i >= 4 * 64 * 64) return;
    int h = i >> 12, d = (i >> 6) & 63, d3 = i & 63;
    float a = 0.f;
    for (int vc = 0; vc < 16; ++vc)
        a += Wv[d * 64 + h * 16 + vc] * Wo[(h * 16 + vc) * 64 + d3];
    Wvo[i] = a;
}

// ---- k_w1l: W1l[l][c][j] = g2[l][c] * Wf1[c][j]  (5 x 64 x 128) ----
__global__ void k_w1l(const float* __restrict__ g2, const float* __restrict__ Wf1,
                      float* __restrict__ W1l) {
    int i = blockIdx.x * blockDim.x + threadIdx.x;
    if (i >= 5 * 64 * 128) return;
    int l = i >> 13, c = (i >> 7) & 63, j = i & 127;
    W1l[i] = g2[l * 64 + c] * Wf1[c * FFH + j];
}

// ---- k_elog: wave-per-edge logits + efs (fast path) ----
// h1 from s_load(edist/emb) x VMEM(We1): zero rdl. msg0 row from P/Q.
__global__ __launch_bounds__(256) void k_elog(
        const float* __restrict__ edist, const float* __restrict__ emb_s,
        const float* __restrict__ emb_r, const float* __restrict__ We1,
        const float* __restrict__ We2, const float* __restrict__ Wa,
        const float* __restrict__ va, const float* __restrict__ pq,
        const float* __restrict__ wigner, const int* __restrict__ species,
        const int* __restrict__ senders, const int* __restrict__ receivers,
        float* __restrict__ logits, float* __restrict__ efsbuf, int N, int E) {
    const int lane = threadIdx.x & 63;
    const int e = __builtin_amdgcn_readfirstlane(blockIdx.x * 4 + (threadIdx.x >> 6));
    if (e >= E) return;
    const int s = senders[e], r = receivers[e];
    float h1a = 0.f, h1b = 0.f;
    {
        const float* __restrict__ eda = edist + (size_t)e * 64;
#pragma unroll 4
        for (int c = 0; c < 64; ++c) {
            const float v = eda[c];
            h1a += v * We1[c * 128 + lane];
            h1b += v * We1[c * 128 + 64 + lane];
        }
        const float* __restrict__ esa = emb_s + (size_t)species[s] * 32;
        const float* __restrict__ era = emb_r + (size_t)species[r] * 32;
#pragma unroll 4
        for (int c = 0; c < 32; ++c) {
            const float v = esa[c];
            h1a += v * We1[(64 + c) * 128 + lane];
            h1b += v * We1[(64 + c) * 128 + 64 + lane];
        }
#pragma unroll 4
        for (int c = 0; c < 32; ++c) {
            const float v = era[c];
            h1a += v * We1[(96 + c) * 128 + lane];
            h1b += v * We1[(96 + c) * 128 + 64 + lane];
        }
    }
    h1a = siluf(h1a); h1b = siluf(h1b);
    float efs = 0.f;
    for (int j = 0; j < 64; ++j) {
        efs += rdlane(h1a, j) * We2[j * 64 + lane];
        efs += rdlane(h1b, j) * We2[(j + 64) * 64 + lane];
    }
    efs = siluf(efs);
    efsbuf[(size_t)e * 64 + lane] = efs;

    // msg0 row: sum_k wig[0][k] * (P[s][k][lane] + Q[r][k][lane])
    const float* __restrict__ wge = wigner + (size_t)e * 475;
    const float* __restrict__ Ps = pq + (size_t)s * 1600;
    const float* __restrict__ Qr = pq + (size_t)N * 1600 + (size_t)r * 1600;
    float m0 = 0.f;
#pragma unroll
    for (int k = 0; k < 25; ++k)
        m0 += wge[k] * (Ps[k * 64 + lane] + Qr[k * 64 + lane]);
    m0 *= efs;
    const float m0g = m0 * sigmf(m0);

    float ava = 0.f, avb = 0.f;
    for (int d = 0; d < 64; ++d) {
        const float sv = rdlane(m0g, d);
        ava += sv * Wa[d * 128 + lane];
        avb += sv * Wa[d * 128 + 64 + lane];
    }
    ava = (ava > 0.f) ? ava : 0.2f * ava;
    avb = (avb > 0.f) ? avb : 0.2f * avb;
    float ra = ava * va[lane];
    float rb = avb * va[64 + lane];
#pragma unroll
    for (int m = 1; m <= 16; m <<= 1) {
        ra += __shfl_xor(ra, m, 64);
        rb += __shfl_xor(rb, m, 64);
    }
    if ((lane & 31) == 0) {
        logits[(size_t)e * NH + (lane >> 5)] = ra;
        logits[(size_t)e * NH + 2 + (lane >> 5)] = rb;
    }
}

// ---- k_edge_logits: old block-per-edge version (fallback path) ----
__global__ __launch_bounds__(128) void k_edge_logits(
        const float* __restrict__ edist, const float* __restrict__ emb_s,
        const float* __restrict__ emb_r, const float* __restrict__ We1,
        const float* __restrict__ We2, const float* __restrict__ Wso2,
        const float* __restrict__ Wa, const float* __restrict__ va,
        const float* __restrict__ wigner, const float* __restrict__ xf,
        const float* __restrict__ g1, const float* __restrict__ scale,
        const int* __restrict__ species, const int* __restrict__ senders,
        const int* __restrict__ receivers, float* __restrict__ logits) {
    int e = blockIdx.x, t = threadIdx.x;
    __shared__ float efin[128], h1[128], efs[64], xr0[128], msg0[64], ared[128];
    int s = senders[e], r = receivers[e];
    if (t < 64)       efin[t] = edist[(size_t)e * 64 + t];
    else if (t < 96)  efin[t] = emb_s[species[s] * 32 + (t - 64)];
    else              efin[t] = emb_r[species[r] * 32 + (t - 96)];
    {
        int c = t & 63;
        int node = (t < 64) ? s : r;
        float sc = scale[node];
        const float* xb = xf + (size_t)node * 1600;
        float a = 0.f;
        for (int k = 0; k < KK; ++k)
            a += wigner[(size_t)e * 475 + k] * xb[k * 64 + c] * g1[c_l_per_k[k] * 64 + c];
        xr0[t] = a * sc;
    }
    __syncthreads();
    {
        float a = 0.f;
        for (int c = 0; c < 128; ++c) a += efin[c] * We1[c * 128 + t];
        h1[t] = siluf(a);
    }
    __syncthreads();
    if (t < 64) {
        float a = 0.f;
        for (int c = 0; c < 128; ++c) a += h1[c] * We2[c * 64 + t];
        efs[t] = siluf(a);
    }
    __syncthreads();
    if (t < 64) {
        float a = 0.f;
        for (int c = 0; c < 128; ++c) a += xr0[c] * Wso2[c * 64 + t];
        a *= efs[t];
        msg0[t] = a * sigmf(a);
    }
    __syncthreads();
    {
        float a = 0.f;
        for (int d = 0; d < 64; ++d) a += msg0[d] * Wa[d * 128 + t];
        float av = (a > 0.f) ? a : 0.2f * a;
        ared[t] = av * va[t];
    }
    __syncthreads();
    if (t < NH) {
        float sum = 0.f;
        for (int a = 0; a < 32; ++a) sum += ared[t * 32 + a];
        logits[(size_t)e * NH + t] = sum;
    }
}

// ---- CSR build ----
__global__ void k_count(const int* __restrict__ receivers, int* __restrict__ counts, int E) {
    int e = blockIdx.x * blockDim.x + threadIdx.x;
    if (e < E) atomicAdd(&counts[receivers[e]], 1);
}

__global__ void k_scan(int* __restrict__ counts, int* __restrict__ offsets, int n) {
    __shared__ int buf[256];
    __shared__ int base_s;
    int t = threadIdx.x;
    if (t == 0) base_s = 0;
    __syncthreads();
    for (int start = 0; start < n; start += 256) {
        int idx = start + t;
        int v = (idx < n) ? counts[idx] : 0;
        buf[t] = v; __syncthreads();
        for (int o = 1; o < 256; o <<= 1) {
            int x = (t >= o) ? buf[t - o] : 0;
            __syncthreads();
            buf[t] += x;
            __syncthreads();
        }
        int incl = buf[t];
        int b = base_s;
        if (idx < n) { offsets[idx] = b + incl - v; counts[idx] = 0; }
        __syncthreads();
        if (t == 0) base_s = b + buf[255];
        __syncthreads();
    }
    if (t == 0) offsets[n] = base_s;
}

__global__ void k_fill(const int* __restrict__ receivers, const int* __restrict__ offsets,
                       int* __restrict__ cursors, int* __restrict__ edge_ids, int E) {
    int e = blockIdx.x * blockDim.x + threadIdx.x;
    if (e >= E) return;
    int r = receivers[e];
    int pos = atomicAdd(&cursors[r], 1);
    edge_ids[offsets[r] + pos] = e;
}

// ---- k_alpha: softmax over incoming edges, alpha written in place over logits ----
__global__ void k_alpha(float* __restrict__ logits, const int* __restrict__ offsets,
                        const int* __restrict__ edge_ids, int N) {
    int i = blockIdx.x * blockDim.x + threadIdx.x;
    if (i >= N * NH) return;
    int n = i >> 2, h = i & 3;
    int o0 = offsets[n], o1 = offsets[n + 1];
    float m = -1e30f;
    for (int j = o0; j < o1; ++j)
        m = fmaxf(m, logits[(size_t)edge_ids[j] * NH + h]);
    float s = 0.f;
    for (int j = o0; j < o1; ++j)
        s += expf(logits[(size_t)edge_ids[j] * NH + h] - m);
    float inv = 1.0f / (s + 1e-9f);
    for (int j = o0; j < o1; ++j) {
        size_t idx = (size_t)edge_ids[j] * NH + h;
        logits[idx] = expf(logits[idx] - m) * inv;
    }
}

// ---- k_tr_fg: transpose from_grid [K][G] -> [G][K] ----
__global__ void k_tr_fg(const float* __restrict__ from_grid, float* __restrict__ fgT) {
    int i = blockIdx.x * blockDim.x + threadIdx.x;
    if (i < GG * KK) {
        int g = i / KK, k = i - g * KK;
        fgT[g * KK + k] = from_grid[k * GG + g];
    }
}

// ---- k_edge_fast: one WAVE per edge using precomputed P/Q, Wvo, efs ----
__global__ __launch_bounds__(256) void k_edge_fast(
        const float* __restrict__ pq, const float* __restrict__ wigner,
        const float* __restrict__ wigner_inv, const float* __restrict__ Wvo,
        const float* __restrict__ efsbuf, const float* __restrict__ alpha,
        const int* __restrict__ senders, const int* __restrict__ receivers,
        float* __restrict__ out, int N, int E) {
    const int lane = threadIdx.x & 63;
    const int e = __builtin_amdgcn_readfirstlane(blockIdx.x * 4 + (threadIdx.x >> 6));
    if (e >= E) return;
    const int s = senders[e];
    const int r = receivers[e];

    const float* __restrict__ Ps = pq + (size_t)s * 1600;
    const float* __restrict__ Qr = pq + (size_t)N * 1600 + (size_t)r * 1600;
    float XW[25];
#pragma unroll
    for (int k = 0; k < 25; ++k) XW[k] = Ps[k * 64 + lane] + Qr[k * 64 + lane];

    const float* __restrict__ wge = wigner + (size_t)e * 475;
    float mp[19];
#pragma unroll
    for (int rr = 0; rr < 19; ++rr) {
        float a = 0.f;
#pragma unroll
        for (int k = 0; k < 25; ++k) a += wge[rr * 25 + k] * XW[k];
        mp[rr] = a;
    }

    const float ef = efsbuf[(size_t)e * 64 + lane];
    const float eg = ef * sigmf(mp[0] * ef);

    const float a0 = alpha[(size_t)e * NH + 0];
    const float a1 = alpha[(size_t)e * NH + 1];
    const float a2 = alpha[(size_t)e * NH + 2];
    const float a3 = alpha[(size_t)e * NH + 3];

    float z[19];
#pragma unroll
    for (int rr = 0; rr < 19; ++rr) z[rr] = 0.f;
    for (int d = 0; d < 64; ++d) {
        float wv = a0 * Wvo[d * 64 + lane]
                 + a1 * Wvo[4096 + d * 64 + lane]
                 + a2 * Wvo[8192 + d * 64 + lane]
                 + a3 * Wvo[12288 + d * 64 + lane];
        wv *= rdlane(eg, d);
#pragma unroll
        for (int rr = 0; rr < 19; ++rr) z[rr] += rdlane(mp[rr], d) * wv;
    }

    const float* __restrict__ wvi = wigner_inv + (size_t)e * 475;
    float* __restrict__ op = out + (size_t)r * 1600;
#pragma unroll
    for (int k = 0; k < 25; ++k) {
        float a = 0.f;
#pragma unroll
        for (int rr = 0; rr < 19; ++rr) a += wvi[k * 19 + rr] * z[rr];
        atomicAdd(&op[k * 64 + lane], a);
    }
}

// ---- k_edge (fallback, round-3 verified) ----
__global__ __launch_bounds__(256) void k_edge(
        const float* __restrict__ xf, const float* __restrict__ wigner,
        const float* __restrict__ wigner_inv, const float* __restrict__ edist,
        const float* __restrict__ emb_s, const float* __restrict__ emb_r,
        const float* __restrict__ We1, const float* __restrict__ We2,
        const float* __restrict__ Wso2, const float* __restrict__ Wv,
        const float* __restrict__ Wo, const float* __restrict__ g1,
        const float* __restrict__ scale, const float* __restrict__ alpha,
        const int* __restrict__ species, const int* __restrict__ senders,
        const int* __restrict__ receivers, float* __restrict__ out, int E) {
    const int lane = threadIdx.x & 63;
    const int e = __builtin_amdgcn_readfirstlane(blockIdx.x * 4 + (threadIdx.x >> 6));
    if (e >= E) return;
    const int s = senders[e];
    const int r = receivers[e];
    const float scs = scale[s], scr = scale[r];

    float g1l[5];
#pragma unroll
    for (int l = 0; l < 5; ++l) g1l[l] = g1[l * 64 + lane];

    float xs[25], xc[25];
#pragma unroll
    for (int k = 0; k < 25; ++k) {
        const float gk = g1l[lpk(k)];
        xs[k] = xf[(size_t)s * 1600 + k * 64 + lane] * scs * gk;
        xc[k] = xf[(size_t)r * 1600 + k * 64 + lane] * scr * gk;
    }

    const float* __restrict__ wge = wigner + (size_t)e * 475;
    float xrs[19], xrc[19];
#pragma unroll
    for (int rr = 0; rr < 19; ++rr) {
        float a = 0.f, b = 0.f;
#pragma unroll
        for (int k = 0; k < 25; ++k) {
            const float w = wge[rr * 25 + k];
            a += w * xs[k];
            b += w * xc[k];
        }
        xrs[rr] = a; xrc[rr] = b;
    }

    float h1a = 0.f, h1b = 0.f;
    {
        const float* __restrict__ eda = edist + (size_t)e * 64;
        const float* __restrict__ esa = emb_s + (size_t)species[s] * 32;
        const float* __restrict__ era = emb_r + (size_t)species[r] * 32;
        for (int c = 0; c < 64; ++c) {
            const float v = eda[c];
            h1a += v * We1[c * 128 + lane];
            h1b += v * We1[c * 128 + 64 + lane];
        }
        for (int c = 0; c < 32; ++c) {
            const float v = esa[c];
            h1a += v * We1[(64 + c) * 128 + lane];
            h1b += v * We1[(64 + c) * 128 + 64 + lane];
        }
        for (int c = 0; c < 32; ++c) {
            const float v = era[c];
            h1a += v * We1[(96 + c) * 128 + lane];
            h1b += v * We1[(96 + c) * 128 + 64 + lane];
        }
        h1a = siluf(h1a); h1b = siluf(h1b);
    }
    float efs = 0.f;
    for (int j = 0; j < 64; ++j) {
        efs += rdlane(h1a, j) * We2[j * 64 + lane];
        efs += rdlane(h1b, j) * We2[(j + 64) * 64 + lane];
    }
    efs = siluf(efs);

    float msg[19];
#pragma unroll
    for (int rr = 0; rr < 19; ++rr) msg[rr] = 0.f;
    for (int c = 0; c < 64; ++c) {
        const float w0 = Wso2[c * 64 + lane];
        const float w1 = Wso2[(64 + c) * 64 + lane];
#pragma unroll
        for (int rr = 0; rr < 19; ++rr)
            msg[rr] += rdlane(xrs[rr], c) * w0 + rdlane(xrc[rr], c) * w1;
    }
#pragma unroll
    for (int rr = 0; rr < 19; ++rr) msg[rr] *= efs;
    const float gate = sigmf(msg[0]);
#pragma unroll
    for (int rr = 0; rr < 19; ++rr) msg[rr] *= gate;

    const int hh = lane >> 4;
    const float al = alpha[(size_t)e * NH + hh];

    float v2[19];
#pragma unroll
    for (int rr = 0; rr < 19; ++rr) v2[rr] = 0.f;
    for (int d = 0; d < 64; ++d) {
        const float w = Wv[d * 64 + lane];
#pragma unroll
        for (int rr = 0; rr < 19; ++rr) v2[rr] += rdlane(msg[rr], d) * w;
    }
#pragma unroll
    for (int rr = 0; rr < 19; ++rr) v2[rr] *= al;

    float z[19];
#pragma unroll
    for (int rr = 0; rr < 19; ++rr) z[rr] = 0.f;
    for (int d = 0; d < 64; ++d) {
        const float w = Wo[d * 64 + lane];
#pragma unroll
        for (int rr = 0; rr < 19; ++rr) z[rr] += rdlane(v2[rr], d) * w;
    }

    const float* __restrict__ wvi = wigner_inv + (size_t)e * 475;
    float* __restrict__ op = out + (size_t)r * 1600;
#pragma unroll
    for (int k = 0; k < 25; ++k) {
        float a = 0.f;
#pragma unroll
        for (int rr = 0; rr < 19; ++rr) a += wvi[k * 19 + rr] * z[rr];
        atomicAdd(&op[k * 64 + lane], a);
    }
}

// ---- k_rms: X = attn_out + residual (in place in out), sc2 per node ----
__global__ void k_rms(const float* __restrict__ xf, float* __restrict__ out,
                      float* __restrict__ sc2) {
    int n = blockIdx.x, t = threadIdx.x;
    __shared__ float red[256];
    float* __restrict__ op = out + (size_t)n * 1600;
    const float* __restrict__ xp = xf + (size_t)n * 1600;
    float ss = 0.f;
    for (int i = t; i < 1600; i += 256) {
        float v = op[i] + xp[i];
        op[i] = v;
        ss += v * v;
    }
    red[t] = ss; __syncthreads();
    for (int s = 128; s > 0; s >>= 1) { if (t < s) red[t] += red[t + s]; __syncthreads(); }
    if (t == 0) sc2[n] = rsqrtf(red[0] / 1600.0f + 1e-6f);
}

// ---- k_ffn1: wave-per-node (lane=j). Y via s_load(X) x VMEM(W1l) -- zero rdl.
// g-loop in j-space; U[128][25] written to Uws (reused pq buffer). ----
__global__ __launch_bounds__(256) void k_ffn1(
        const float* __restrict__ Xg, const float* __restrict__ sc2buf,
        const float* __restrict__ W1l, const float* __restrict__ to_grid,
        const float* __restrict__ fgT, float* __restrict__ Uws, int N) {
    const int lane = threadIdx.x & 63;
    const int n = __builtin_amdgcn_readfirstlane(blockIdx.x * 4 + (threadIdx.x >> 6));
    if (n >= N) return;
    const float sc2 = sc2buf[n];
    const float* __restrict__ xrow = Xg + (size_t)n * 1600;

    // Y[k][j] = sc2 * sum_c s(X[k][c]) * W1l[l(k)][c][j]
    float Ya[25], Yb[25];
#pragma unroll
    for (int k = 0; k < 25; ++k) {
        const float* __restrict__ wl = W1l + (size_t)lpk(k) * 8192;
        const float* __restrict__ xr = xrow + k * 64;
        float a = 0.f, b = 0.f;
#pragma unroll 4
        for (int c = 0; c < 64; ++c) {
            const float xv = xr[c];
            a += xv * wl[c * 128 + lane];
            b += xv * wl[c * 128 + 64 + lane];
        }
        Ya[k] = a * sc2;
        Yb[k] = b * sc2;
    }

    // g-loop: h = silu(tg.Y); U += fg*h   (all lane=j, pure s x v FMA)
    float Ua[25], Ub[25];
#pragma unroll
    for (int k = 0; k < 25; ++k) { Ua[k] = 0.f; Ub[k] = 0.f; }
#pragma unroll 2
    for (int g = 0; g < GG; ++g) {
        const float* __restrict__ tg = to_grid + (size_t)g * KK;
        const float* __restrict__ fg = fgT + (size_t)g * KK;
        float ha = 0.f, hb = 0.f;
#pragma unroll
        for (int k = 0; k < 25; ++k) {
            const float t = tg[k];
            ha += t * Ya[k];
            hb += t * Yb[k];
        }
        ha = siluf(ha); hb = siluf(hb);
#pragma unroll
        for (int k = 0; k < 25; ++k) {
            const float f = fg[k];
            Ua[k] += f * ha;
            Ub[k] += f * hb;
        }
    }

    // store U in [n][j][k] layout (rows of 25 for k_ffn2's s_loads)
    float* __restrict__ ua = Uws + ((size_t)n * 128 + lane) * 25;
    float* __restrict__ ub = Uws + ((size_t)n * 128 + 64 + lane) * 25;
#pragma unroll
    for (int k = 0; k < 25; ++k) {
        ua[k] = Ua[k];
        ub[k] = Ub[k];
    }
}

// ---- k_ffn2: wave-per-node (lane=c). racc = sum_j s(U[j][k]) * Wf2[j][c];
// out = X + racc -- zero rdl. ----
__global__ __launch_bounds__(256) void k_ffn2(
        const float* __restrict__ Uws, const float* __restrict__ Wf2,
        float* __restrict__ out, int N) {
    const int lane = threadIdx.x & 63;
    const int n = __builtin_amdgcn_readfirstlane(blockIdx.x * 4 + (threadIdx.x >> 6));
    if (n >= N) return;
    const float* __restrict__ urow = Uws + (size_t)n * 3200;
    float racc[25];
#pragma unroll
    for (int k = 0; k < 25; ++k) racc[k] = 0.f;
#pragma unroll 2
    for (int j = 0; j < 128; ++j) {
        const float wv = Wf2[j * 64 + lane];
        const float* __restrict__ up = urow + j * 25;
#pragma unroll
        for (int k = 0; k < 25; ++k) racc[k] += up[k] * wv;
    }
    float* __restrict__ op = out + (size_t)n * 1600;
#pragma unroll
    for (int k = 0; k < 25; ++k)
        op[k * 64 + lane] = op[k * 64 + lane] + racc[k];
}

// ---- k_ffn (fallback, round-4 verified) ----
__global__ __launch_bounds__(256) void k_ffn(
        const float* __restrict__ xf, const float* __restrict__ g2,
        const float* __restrict__ to_grid, const float* __restrict__ fgT,
        const float* __restrict__ Wf1, const float* __restrict__ Wf2,
        float* __restrict__ out, int N) {
    const int lane = threadIdx.x & 63;
    const int n = __builtin_amdgcn_readfirstlane(blockIdx.x * 4 + (threadIdx.x >> 6));
    if (n >= N) return;
    const float* __restrict__ oin = out + (size_t)n * 1600;
    const float* __restrict__ xin = xf + (size_t)n * 1600;

    float xn[25];
    float ss = 0.f;
#pragma unroll
    for (int k = 0; k < 25; ++k) {
        const float X = oin[k * 64 + lane] + xin[k * 64 + lane];
        xn[k] = X;
        ss += X * X;
    }
#pragma unroll
    for (int m = 1; m < 64; m <<= 1) ss += __shfl_xor(ss, m, 64);
    const float sc2 = rsqrtf(ss * (1.0f / 1600.f) + 1e-6f);
#pragma unroll
    for (int k = 0; k < 25; ++k) xn[k] *= sc2 * g2[lpk(k) * 64 + lane];

    float Ya[25], Yb[25];
#pragma unroll
    for (int k = 0; k < 25; ++k) { Ya[k] = 0.f; Yb[k] = 0.f; }
    for (int c = 0; c < 64; ++c) {
        const float w0 = Wf1[c * FFH + lane];
        const float w1 = Wf1[c * FFH + 64 + lane];
#pragma unroll
        for (int k = 0; k < 25; ++k) {
            const float sv = rdlane(xn[k], c);
            Ya[k] += sv * w0;
            Yb[k] += sv * w1;
        }
    }

    float Ua[25], Ub[25];
#pragma unroll
    for (int k = 0; k < 25; ++k) { Ua[k] = 0.f; Ub[k] = 0.f; }
#pragma unroll 2
    for (int g = 0; g < GG; ++g) {
        const float* __restrict__ tg = to_grid + (size_t)g * KK;
        const float* __restrict__ fg = fgT + (size_t)g * KK;
        float ha = 0.f, hb = 0.f;
#pragma unroll
        for (int k = 0; k < 25; ++k) {
            const float t = tg[k];
            ha += t * Ya[k];
            hb += t * Yb[k];
        }
        ha = siluf(ha); hb = siluf(hb);
#pragma unroll
        for (int k = 0; k < 25; ++k) {
            const float f = fg[k];
            Ua[k] += f * ha;
            Ub[k] += f * hb;
        }
    }

    float racc[25];
#pragma unroll
    for (int k = 0; k < 25; ++k) racc[k] = 0.f;
    for (int j = 0; j < 64; ++j) {
        const float w0 = Wf2[j * 64 + lane];
        const float w1 = Wf2[(64 + j) * 64 + lane];
#pragma unroll
        for (int k = 0; k < 25; ++k)
            racc[k] += rdlane(Ua[k], j) * w0 + rdlane(Ub[k], j) * w1;
    }

    float* __restrict__ op = out + (size_t)n * 1600;
#pragma unroll
    for (int k = 0; k < 25; ++k)
        op[k * 64 + lane] = oin[k * 64 + lane] + xin[k * 64 + lane] + racc[k];
}

extern "C" void kernel_launch(void* const* d_in, const int* in_sizes, int n_in,
                              void* d_out, int out_size, void* d_ws, size_t ws_size,
                              hipStream_t stream) {
    const float* node_feats     = (const float*)d_in[0];
    const float* edge_distances = (const float*)d_in[1];
    const float* wigner         = (const float*)d_in[2];
    const float* wigner_inv     = (const float*)d_in[3];
    const int*   node_species   = (const int*)  d_in[4];
    const int*   senders        = (const int*)  d_in[5];
    const int*   receivers      = (const int*)  d_in[6];
    const float* g1             = (const float*)d_in[7];
    const float* g2             = (const float*)d_in[8];
    const float* emb_s          = (const float*)d_in[9];
    const float* emb_r          = (const float*)d_in[10];
    const float* We1            = (const float*)d_in[11];
    const float* We2            = (const float*)d_in[12];
    const float* Wso2           = (const float*)d_in[13];
    const float* Wa             = (const float*)d_in[14];
    const float* va             = (const float*)d_in[15];
    const float* Wv             = (const float*)d_in[16];
    const float* Wo             = (const float*)d_in[17];
    const float* to_grid        = (const float*)d_in[18];
    const float* from_grid      = (const float*)d_in[19];
    const float* Wf1            = (const float*)d_in[20];
    const float* Wf2            = (const float*)d_in[21];

    const int N = in_sizes[4];
    const int E = in_sizes[5];

    char* ws = (char*)d_ws;
    size_t o = 0;
    float* scale    = (float*)(ws + o); o += (size_t)N * 4;
    int*   counts   = (int*)  (ws + o); o += (size_t)N * 4;
    int*   offsets  = (int*)  (ws + o); o += (size_t)(N + 1) * 4;
    int*   edge_ids = (int*)  (ws + o); o += (size_t)E * 4;
    float* logits   = (float*)(ws + o); o += (size_t)E * NH * 4;
    float* fgT      = (float*)(ws + o); o += (size_t)GG * KK * 4;
    // fast-path buffers (gated on ws_size)
    size_t o_fast = o;
    float* efsbuf = (float*)(ws + o_fast); o_fast += (size_t)E * 64 * 4;
    float* Wvo    = (float*)(ws + o_fast); o_fast += (size_t)4 * 64 * 64 * 4;
    float* pq     = (float*)(ws + o_fast); o_fast += (size_t)N * 3200 * 4; // reused as Uws
    float* W1l    = (float*)(ws + o_fast); o_fast += (size_t)5 * 64 * 128 * 4;
    float* sc2    = (float*)(ws + o_fast); o_fast += (size_t)N * 4;
    const bool fast = (ws_size >= o_fast);

    hipMemsetAsync(counts, 0, (size_t)N * 4, stream);
    hipMemsetAsync(d_out, 0, (size_t)N * 1600 * 4, stream);

    k_tr_fg<<<(GG * KK + 255) / 256, 256, 0, stream>>>(from_grid, fgT);
    if (fast) {
        k_pq<<<(N + 3) / 4, 256, 0, stream>>>(node_feats, g1, Wso2, pq, N);
        k_wvo<<<64, 256, 0, stream>>>(Wv, Wo, Wvo);
        k_w1l<<<(5 * 64 * 128 + 255) / 256, 256, 0, stream>>>(g2, Wf1, W1l);
        k_elog<<<(E + 3) / 4, 256, 0, stream>>>(edge_distances, emb_s, emb_r, We1,
                                                We2, Wa, va, pq, wigner, node_species,
                                                senders, receivers, logits, efsbuf,
                                                N, E);
        k_count<<<(E + 255) / 256, 256, 0, stream>>>(receivers, counts, E);
        k_scan<<<1, 256, 0, stream>>>(counts, offsets, N);
        k_fill<<<(E + 255) / 256, 256, 0, stream>>>(receivers, offsets, counts,
                                                    edge_ids, E);
        k_alpha<<<(N * NH + 255) / 256, 256, 0, stream>>>(logits, offsets, edge_ids, N);
        k_edge_fast<<<(E + 3) / 4, 256, 0, stream>>>(pq, wigner, wigner_inv, Wvo,
                                                     efsbuf, logits, senders, receivers,
                                                     (float*)d_out, N, E);
        // FFN: X := attn_out + residual (in d_out), then factorized grid FFN
        k_rms<<<N, 256, 0, stream>>>(node_feats, (float*)d_out, sc2);
        k_ffn1<<<(N + 3) / 4, 256, 0, stream>>>((const float*)d_out, sc2, W1l,
                                                to_grid, fgT, pq, N);
        k_ffn2<<<(N + 3) / 4, 256, 0, stream>>>(pq, Wf2, (float*)d_out, N);
    } else {
        k_scale<<<N, 256, 0, stream>>>(node_feats, scale);
        k_edge_logits<<<E, 128, 0, stream>>>(edge_distances, emb_s, emb_r, We1, We2,
                                             Wso2, Wa, va, wigner, node_feats, g1,
                                             scale, node_species, senders, receivers,
                                             logits);
        k_count<<<(E + 255) / 256, 256, 0, stream>>>(receivers, counts, E);
        k_scan<<<1, 256, 0, stream>>>(counts, offsets, N);
        k_fill<<<(E + 255) / 256, 256, 0, stream>>>(receivers, offsets, counts,
                                                    edge_ids, E);
        k_alpha<<<(N * NH + 255) / 256, 256, 0, stream>>>(logits, offsets, edge_ids, N);
        k_edge<<<(E + 3) / 4, 256, 0, stream>>>(node_feats, wigner, wigner_inv,
                                                edge_distances, emb_s, emb_r, We1, We2,
                                                Wso2, Wv, Wo, g1, scale, logits,
                                                node_species, senders, receivers,
                                                (float*)d_out, E);
        k_ffn<<<(N + 3) / 4, 256, 0, stream>>>(node_feats, g2, to_grid, fgT, Wf1, Wf2,
                                               (float*)d_out, N);
    }
}

// Round 6
// 1229.361 us; speedup vs baseline: 5.3404x; 1.1403x over previous
//
#include <hip/hip_runtime.h>

#define KK 25
#define KRR 19
#define NH 4
#define GG 100
#define FFH 128

__device__ __constant__ int c_l_per_k[25] = {0, 1,1,1, 2,2,2,2,2,
                                             3,3,3,3,3,3,3,
                                             4,4,4,4,4,4,4,4,4};

__device__ __forceinline__ float siluf(float x) { return x / (1.0f + __expf(-x)); }
__device__ __forceinline__ float sigmf(float x) { return 1.0f / (1.0f + __expf(-x)); }

// compile-time l(k) for fully-unrolled loops
__device__ __forceinline__ constexpr int lpk(int k) {
    return (k == 0) ? 0 : (k < 4) ? 1 : (k < 9) ? 2 : (k < 16) ? 3 : 4;
}

// cross-lane extract on the VALU pipe (not LDS): v_readlane_b32
__device__ __forceinline__ float rdlane(float x, int l) {
    return __int_as_float(__builtin_amdgcn_readlane(__float_as_int(x), l));
}

// ---- k_scale: per-node RMS scale (f32) -- fallback path only ----
__global__ void k_scale(const float* __restrict__ xf, float* __restrict__ scale) {
    int n = blockIdx.x, t = threadIdx.x;
    __shared__ float red[256];
    const float* xp = xf + (size_t)n * 1600;
    float ss = 0.f;
    for (int i = t; i < 1600; i += 256) { float v = xp[i]; ss += v * v; }
    red[t] = ss; __syncthreads();
    for (int s = 128; s > 0; s >>= 1) { if (t < s) red[t] += red[t + s]; __syncthreads(); }
    if (t == 0) scale[n] = rsqrtf(red[0] / 1600.0f + 1e-6f);
}

// ---- k_pq: per-node P = xnorm @ Wso2_top, Q = xnorm @ Wso2_bot (rms inline) ----
__global__ __launch_bounds__(256) void k_pq(
        const float* __restrict__ xf, const float* __restrict__ g1,
        const float* __restrict__ Wso2, float* __restrict__ pq, int N) {
    const int lane = threadIdx.x & 63;
    const int n = __builtin_amdgcn_readfirstlane(blockIdx.x * 4 + (threadIdx.x >> 6));
    if (n >= N) return;
    float xn[25];
    float ss = 0.f;
#pragma unroll
    for (int k = 0; k < 25; ++k) {
        const float v = xf[(size_t)n * 1600 + k * 64 + lane];
        xn[k] = v;
        ss += v * v;
    }
#pragma unroll
    for (int m = 1; m < 64; m <<= 1) ss += __shfl_xor(ss, m, 64);
    const float sc = rsqrtf(ss * (1.0f / 1600.f) + 1e-6f);
#pragma unroll
    for (int k = 0; k < 25; ++k) xn[k] *= sc * g1[lpk(k) * 64 + lane];
    float P[25], Q[25];
#pragma unroll
    for (int k = 0; k < 25; ++k) { P[k] = 0.f; Q[k] = 0.f; }
    for (int c = 0; c < 64; ++c) {
        const float w0 = Wso2[c * 64 + lane];
        const float w1 = Wso2[(64 + c) * 64 + lane];
#pragma unroll
        for (int k = 0; k < 25; ++k) {
            const float sv = rdlane(xn[k], c);
            P[k] += sv * w0;
            Q[k] += sv * w1;
        }
    }
    float* __restrict__ pp = pq + (size_t)n * 1600;
    float* __restrict__ qp = pq + (size_t)N * 1600 + (size_t)n * 1600;
#pragma unroll
    for (int k = 0; k < 25; ++k) {
        pp[k * 64 + lane] = P[k];
        qp[k * 64 + lane] = Q[k];
    }
}

// ---- k_wvo: Wvo[h] = Wv[:, h*16:(h+1)*16] @ Wo[h*16:(h+1)*16, :] ----
__global__ void k_wvo(const float* __restrict__ Wv, const float* __restrict__ Wo,
                      float* __restrict__ Wvo) {
    int i = blockIdx.x * blockDim.x + threadIdx.x;
    if (i >= 4 * 64 * 64) return;
    int h = i >> 12, d = (i >> 6) & 63, d3 = i & 63;
    float a = 0.f;
    for (int vc = 0; vc < 16; ++vc)
        a += Wv[d * 64 + h * 16 + vc] * Wo[(h * 16 + vc) * 64 + d3];
    Wvo[i] = a;
}

// ---- k_w1l: W1l[l][c][j] = g2[l][c] * Wf1[c][j]  (5 x 64 x 128) ----
__global__ void k_w1l(const float* __restrict__ g2, const float* __restrict__ Wf1,
                      float* __restrict__ W1l) {
    int i = blockIdx.x * blockDim.x + threadIdx.x;
    if (i >= 5 * 64 * 128) return;
    int l = i >> 13, c = (i >> 7) & 63, j = i & 127;
    W1l[i] = g2[l * 64 + c] * Wf1[c * FFH + j];
}

// ---- k_elog: wave-per-edge logits + efs (fast path) ----
__global__ __launch_bounds__(256) void k_elog(
        const float* __restrict__ edist, const float* __restrict__ emb_s,
        const float* __restrict__ emb_r, const float* __restrict__ We1,
        const float* __restrict__ We2, const float* __restrict__ Wa,
        const float* __restrict__ va, const float* __restrict__ pq,
        const float* __restrict__ wigner, const int* __restrict__ species,
        const int* __restrict__ senders, const int* __restrict__ receivers,
        float* __restrict__ logits, float* __restrict__ efsbuf, int N, int E) {
    const int lane = threadIdx.x & 63;
    const int e = __builtin_amdgcn_readfirstlane(blockIdx.x * 4 + (threadIdx.x >> 6));
    if (e >= E) return;
    const int s = senders[e], r = receivers[e];
    float h1a = 0.f, h1b = 0.f;
    {
        const float* __restrict__ eda = edist + (size_t)e * 64;
#pragma unroll 4
        for (int c = 0; c < 64; ++c) {
            const float v = eda[c];
            h1a += v * We1[c * 128 + lane];
            h1b += v * We1[c * 128 + 64 + lane];
        }
        const float* __restrict__ esa = emb_s + (size_t)species[s] * 32;
        const float* __restrict__ era = emb_r + (size_t)species[r] * 32;
#pragma unroll 4
        for (int c = 0; c < 32; ++c) {
            const float v = esa[c];
            h1a += v * We1[(64 + c) * 128 + lane];
            h1b += v * We1[(64 + c) * 128 + 64 + lane];
        }
#pragma unroll 4
        for (int c = 0; c < 32; ++c) {
            const float v = era[c];
            h1a += v * We1[(96 + c) * 128 + lane];
            h1b += v * We1[(96 + c) * 128 + 64 + lane];
        }
    }
    h1a = siluf(h1a); h1b = siluf(h1b);
    float efs = 0.f;
    for (int j = 0; j < 64; ++j) {
        efs += rdlane(h1a, j) * We2[j * 64 + lane];
        efs += rdlane(h1b, j) * We2[(j + 64) * 64 + lane];
    }
    efs = siluf(efs);
    efsbuf[(size_t)e * 64 + lane] = efs;

    const float* __restrict__ wge = wigner + (size_t)e * 475;
    const float* __restrict__ Ps = pq + (size_t)s * 1600;
    const float* __restrict__ Qr = pq + (size_t)N * 1600 + (size_t)r * 1600;
    float m0 = 0.f;
#pragma unroll
    for (int k = 0; k < 25; ++k)
        m0 += wge[k] * (Ps[k * 64 + lane] + Qr[k * 64 + lane]);
    m0 *= efs;
    const float m0g = m0 * sigmf(m0);

    float ava = 0.f, avb = 0.f;
    for (int d = 0; d < 64; ++d) {
        const float sv = rdlane(m0g, d);
        ava += sv * Wa[d * 128 + lane];
        avb += sv * Wa[d * 128 + 64 + lane];
    }
    ava = (ava > 0.f) ? ava : 0.2f * ava;
    avb = (avb > 0.f) ? avb : 0.2f * avb;
    float ra = ava * va[lane];
    float rb = avb * va[64 + lane];
#pragma unroll
    for (int m = 1; m <= 16; m <<= 1) {
        ra += __shfl_xor(ra, m, 64);
        rb += __shfl_xor(rb, m, 64);
    }
    if ((lane & 31) == 0) {
        logits[(size_t)e * NH + (lane >> 5)] = ra;
        logits[(size_t)e * NH + 2 + (lane >> 5)] = rb;
    }
}

// ---- k_edge_logits: old block-per-edge version (fallback path) ----
__global__ __launch_bounds__(128) void k_edge_logits(
        const float* __restrict__ edist, const float* __restrict__ emb_s,
        const float* __restrict__ emb_r, const float* __restrict__ We1,
        const float* __restrict__ We2, const float* __restrict__ Wso2,
        const float* __restrict__ Wa, const float* __restrict__ va,
        const float* __restrict__ wigner, const float* __restrict__ xf,
        const float* __restrict__ g1, const float* __restrict__ scale,
        const int* __restrict__ species, const int* __restrict__ senders,
        const int* __restrict__ receivers, float* __restrict__ logits) {
    int e = blockIdx.x, t = threadIdx.x;
    __shared__ float efin[128], h1[128], efs[64], xr0[128], msg0[64], ared[128];
    int s = senders[e], r = receivers[e];
    if (t < 64)       efin[t] = edist[(size_t)e * 64 + t];
    else if (t < 96)  efin[t] = emb_s[species[s] * 32 + (t - 64)];
    else              efin[t] = emb_r[species[r] * 32 + (t - 96)];
    {
        int c = t & 63;
        int node = (t < 64) ? s : r;
        float sc = scale[node];
        const float* xb = xf + (size_t)node * 1600;
        float a = 0.f;
        for (int k = 0; k < KK; ++k)
            a += wigner[(size_t)e * 475 + k] * xb[k * 64 + c] * g1[c_l_per_k[k] * 64 + c];
        xr0[t] = a * sc;
    }
    __syncthreads();
    {
        float a = 0.f;
        for (int c = 0; c < 128; ++c) a += efin[c] * We1[c * 128 + t];
        h1[t] = siluf(a);
    }
    __syncthreads();
    if (t < 64) {
        float a = 0.f;
        for (int c = 0; c < 128; ++c) a += h1[c] * We2[c * 64 + t];
        efs[t] = siluf(a);
    }
    __syncthreads();
    if (t < 64) {
        float a = 0.f;
        for (int c = 0; c < 128; ++c) a += xr0[c] * Wso2[c * 64 + t];
        a *= efs[t];
        msg0[t] = a * sigmf(a);
    }
    __syncthreads();
    {
        float a = 0.f;
        for (int d = 0; d < 64; ++d) a += msg0[d] * Wa[d * 128 + t];
        float av = (a > 0.f) ? a : 0.2f * a;
        ared[t] = av * va[t];
    }
    __syncthreads();
    if (t < NH) {
        float sum = 0.f;
        for (int a = 0; a < 32; ++a) sum += ared[t * 32 + a];
        logits[(size_t)e * NH + t] = sum;
    }
}

// ---- CSR build ----
__global__ void k_count(const int* __restrict__ receivers, int* __restrict__ counts, int E) {
    int e = blockIdx.x * blockDim.x + threadIdx.x;
    if (e < E) atomicAdd(&counts[receivers[e]], 1);
}

__global__ void k_scan(int* __restrict__ counts, int* __restrict__ offsets, int n) {
    __shared__ int buf[256];
    __shared__ int base_s;
    int t = threadIdx.x;
    if (t == 0) base_s = 0;
    __syncthreads();
    for (int start = 0; start < n; start += 256) {
        int idx = start + t;
        int v = (idx < n) ? counts[idx] : 0;
        buf[t] = v; __syncthreads();
        for (int o = 1; o < 256; o <<= 1) {
            int x = (t >= o) ? buf[t - o] : 0;
            __syncthreads();
            buf[t] += x;
            __syncthreads();
        }
        int incl = buf[t];
        int b = base_s;
        if (idx < n) { offsets[idx] = b + incl - v; counts[idx] = 0; }
        __syncthreads();
        if (t == 0) base_s = b + buf[255];
        __syncthreads();
    }
    if (t == 0) offsets[n] = base_s;
}

__global__ void k_fill(const int* __restrict__ receivers, const int* __restrict__ offsets,
                       int* __restrict__ cursors, int* __restrict__ edge_ids, int E) {
    int e = blockIdx.x * blockDim.x + threadIdx.x;
    if (e >= E) return;
    int r = receivers[e];
    int pos = atomicAdd(&cursors[r], 1);
    edge_ids[offsets[r] + pos] = e;
}

// ---- k_alpha: softmax over incoming edges, alpha written in place over logits ----
__global__ void k_alpha(float* __restrict__ logits, const int* __restrict__ offsets,
                        const int* __restrict__ edge_ids, int N) {
    int i = blockIdx.x * blockDim.x + threadIdx.x;
    if (i >= N * NH) return;
    int n = i >> 2, h = i & 3;
    int o0 = offsets[n], o1 = offsets[n + 1];
    float m = -1e30f;
    for (int j = o0; j < o1; ++j)
        m = fmaxf(m, logits[(size_t)edge_ids[j] * NH + h]);
    float s = 0.f;
    for (int j = o0; j < o1; ++j)
        s += expf(logits[(size_t)edge_ids[j] * NH + h] - m);
    float inv = 1.0f / (s + 1e-9f);
    for (int j = o0; j < o1; ++j) {
        size_t idx = (size_t)edge_ids[j] * NH + h;
        logits[idx] = expf(logits[idx] - m) * inv;
    }
}

// ---- k_tr_fg: transpose from_grid [K][G] -> [G][K] ----
__global__ void k_tr_fg(const float* __restrict__ from_grid, float* __restrict__ fgT) {
    int i = blockIdx.x * blockDim.x + threadIdx.x;
    if (i < GG * KK) {
        int g = i / KK, k = i - g * KK;
        fgT[g * KK + k] = from_grid[k * GG + g];
    }
}

// ---- k_edge_fast: one WAVE per edge using precomputed P/Q, Wvo, efs ----
__global__ __launch_bounds__(256) void k_edge_fast(
        const float* __restrict__ pq, const float* __restrict__ wigner,
        const float* __restrict__ wigner_inv, const float* __restrict__ Wvo,
        const float* __restrict__ efsbuf, const float* __restrict__ alpha,
        const int* __restrict__ senders, const int* __restrict__ receivers,
        float* __restrict__ out, int N, int E) {
    const int lane = threadIdx.x & 63;
    const int e = __builtin_amdgcn_readfirstlane(blockIdx.x * 4 + (threadIdx.x >> 6));
    if (e >= E) return;
    const int s = senders[e];
    const int r = receivers[e];

    const float* __restrict__ Ps = pq + (size_t)s * 1600;
    const float* __restrict__ Qr = pq + (size_t)N * 1600 + (size_t)r * 1600;
    float XW[25];
#pragma unroll
    for (int k = 0; k < 25; ++k) XW[k] = Ps[k * 64 + lane] + Qr[k * 64 + lane];

    const float* __restrict__ wge = wigner + (size_t)e * 475;
    float mp[19];
#pragma unroll
    for (int rr = 0; rr < 19; ++rr) {
        float a = 0.f;
#pragma unroll
        for (int k = 0; k < 25; ++k) a += wge[rr * 25 + k] * XW[k];
        mp[rr] = a;
    }

    const float ef = efsbuf[(size_t)e * 64 + lane];
    const float eg = ef * sigmf(mp[0] * ef);

    const float a0 = alpha[(size_t)e * NH + 0];
    const float a1 = alpha[(size_t)e * NH + 1];
    const float a2 = alpha[(size_t)e * NH + 2];
    const float a3 = alpha[(size_t)e * NH + 3];

    float z[19];
#pragma unroll
    for (int rr = 0; rr < 19; ++rr) z[rr] = 0.f;
    for (int d = 0; d < 64; ++d) {
        float wv = a0 * Wvo[d * 64 + lane]
                 + a1 * Wvo[4096 + d * 64 + lane]
                 + a2 * Wvo[8192 + d * 64 + lane]
                 + a3 * Wvo[12288 + d * 64 + lane];
        wv *= rdlane(eg, d);
#pragma unroll
        for (int rr = 0; rr < 19; ++rr) z[rr] += rdlane(mp[rr], d) * wv;
    }

    const float* __restrict__ wvi = wigner_inv + (size_t)e * 475;
    float* __restrict__ op = out + (size_t)r * 1600;
#pragma unroll
    for (int k = 0; k < 25; ++k) {
        float a = 0.f;
#pragma unroll
        for (int rr = 0; rr < 19; ++rr) a += wvi[k * 19 + rr] * z[rr];
        atomicAdd(&op[k * 64 + lane], a);
    }
}

// ---- k_edge (fallback, round-3 verified) ----
__global__ __launch_bounds__(256) void k_edge(
        const float* __restrict__ xf, const float* __restrict__ wigner,
        const float* __restrict__ wigner_inv, const float* __restrict__ edist,
        const float* __restrict__ emb_s, const float* __restrict__ emb_r,
        const float* __restrict__ We1, const float* __restrict__ We2,
        const float* __restrict__ Wso2, const float* __restrict__ Wv,
        const float* __restrict__ Wo, const float* __restrict__ g1,
        const float* __restrict__ scale, const float* __restrict__ alpha,
        const int* __restrict__ species, const int* __restrict__ senders,
        const int* __restrict__ receivers, float* __restrict__ out, int E) {
    const int lane = threadIdx.x & 63;
    const int e = __builtin_amdgcn_readfirstlane(blockIdx.x * 4 + (threadIdx.x >> 6));
    if (e >= E) return;
    const int s = senders[e];
    const int r = receivers[e];
    const float scs = scale[s], scr = scale[r];

    float g1l[5];
#pragma unroll
    for (int l = 0; l < 5; ++l) g1l[l] = g1[l * 64 + lane];

    float xs[25], xc[25];
#pragma unroll
    for (int k = 0; k < 25; ++k) {
        const float gk = g1l[lpk(k)];
        xs[k] = xf[(size_t)s * 1600 + k * 64 + lane] * scs * gk;
        xc[k] = xf[(size_t)r * 1600 + k * 64 + lane] * scr * gk;
    }

    const float* __restrict__ wge = wigner + (size_t)e * 475;
    float xrs[19], xrc[19];
#pragma unroll
    for (int rr = 0; rr < 19; ++rr) {
        float a = 0.f, b = 0.f;
#pragma unroll
        for (int k = 0; k < 25; ++k) {
            const float w = wge[rr * 25 + k];
            a += w * xs[k];
            b += w * xc[k];
        }
        xrs[rr] = a; xrc[rr] = b;
    }

    float h1a = 0.f, h1b = 0.f;
    {
        const float* __restrict__ eda = edist + (size_t)e * 64;
        const float* __restrict__ esa = emb_s + (size_t)species[s] * 32;
        const float* __restrict__ era = emb_r + (size_t)species[r] * 32;
        for (int c = 0; c < 64; ++c) {
            const float v = eda[c];
            h1a += v * We1[c * 128 + lane];
            h1b += v * We1[c * 128 + 64 + lane];
        }
        for (int c = 0; c < 32; ++c) {
            const float v = esa[c];
            h1a += v * We1[(64 + c) * 128 + lane];
            h1b += v * We1[(64 + c) * 128 + 64 + lane];
        }
        for (int c = 0; c < 32; ++c) {
            const float v = era[c];
            h1a += v * We1[(96 + c) * 128 + lane];
            h1b += v * We1[(96 + c) * 128 + 64 + lane];
        }
        h1a = siluf(h1a); h1b = siluf(h1b);
    }
    float efs = 0.f;
    for (int j = 0; j < 64; ++j) {
        efs += rdlane(h1a, j) * We2[j * 64 + lane];
        efs += rdlane(h1b, j) * We2[(j + 64) * 64 + lane];
    }
    efs = siluf(efs);

    float msg[19];
#pragma unroll
    for (int rr = 0; rr < 19; ++rr) msg[rr] = 0.f;
    for (int c = 0; c < 64; ++c) {
        const float w0 = Wso2[c * 64 + lane];
        const float w1 = Wso2[(64 + c) * 64 + lane];
#pragma unroll
        for (int rr = 0; rr < 19; ++rr)
            msg[rr] += rdlane(xrs[rr], c) * w0 + rdlane(xrc[rr], c) * w1;
    }
#pragma unroll
    for (int rr = 0; rr < 19; ++rr) msg[rr] *= efs;
    const float gate = sigmf(msg[0]);
#pragma unroll
    for (int rr = 0; rr < 19; ++rr) msg[rr] *= gate;

    const int hh = lane >> 4;
    const float al = alpha[(size_t)e * NH + hh];

    float v2[19];
#pragma unroll
    for (int rr = 0; rr < 19; ++rr) v2[rr] = 0.f;
    for (int d = 0; d < 64; ++d) {
        const float w = Wv[d * 64 + lane];
#pragma unroll
        for (int rr = 0; rr < 19; ++rr) v2[rr] += rdlane(msg[rr], d) * w;
    }
#pragma unroll
    for (int rr = 0; rr < 19; ++rr) v2[rr] *= al;

    float z[19];
#pragma unroll
    for (int rr = 0; rr < 19; ++rr) z[rr] = 0.f;
    for (int d = 0; d < 64; ++d) {
        const float w = Wo[d * 64 + lane];
#pragma unroll
        for (int rr = 0; rr < 19; ++rr) z[rr] += rdlane(v2[rr], d) * w;
    }

    const float* __restrict__ wvi = wigner_inv + (size_t)e * 475;
    float* __restrict__ op = out + (size_t)r * 1600;
#pragma unroll
    for (int k = 0; k < 25; ++k) {
        float a = 0.f;
#pragma unroll
        for (int rr = 0; rr < 19; ++rr) a += wvi[k * 19 + rr] * z[rr];
        atomicAdd(&op[k * 64 + lane], a);
    }
}

// ---- k_rms: X = attn_out + residual (in place in out), sc2 per node ----
__global__ void k_rms(const float* __restrict__ xf, float* __restrict__ out,
                      float* __restrict__ sc2) {
    int n = blockIdx.x, t = threadIdx.x;
    __shared__ float red[256];
    float* __restrict__ op = out + (size_t)n * 1600;
    const float* __restrict__ xp = xf + (size_t)n * 1600;
    float ss = 0.f;
    for (int i = t; i < 1600; i += 256) {
        float v = op[i] + xp[i];
        op[i] = v;
        ss += v * v;
    }
    red[t] = ss; __syncthreads();
    for (int s = 128; s > 0; s >>= 1) { if (t < s) red[t] += red[t + s]; __syncthreads(); }
    if (t == 0) sc2[n] = rsqrtf(red[0] / 1600.0f + 1e-6f);
}

// ---- k_ffn1: wave-per-node (lane=j). Y via s_load(X) x cached W1l -- zero rdl.
// c-OUTER loop: w0l/w1l (5 l-variants) loaded once per c, reused across all 25 k.
// g-loop in j-space; U[128][25] written to Uws (reused pq buffer). ----
__global__ __launch_bounds__(256) void k_ffn1(
        const float* __restrict__ Xg, const float* __restrict__ sc2buf,
        const float* __restrict__ W1l, const float* __restrict__ to_grid,
        const float* __restrict__ fgT, float* __restrict__ Uws, int N) {
    const int lane = threadIdx.x & 63;
    const int n = __builtin_amdgcn_readfirstlane(blockIdx.x * 4 + (threadIdx.x >> 6));
    if (n >= N) return;
    const float sc2 = sc2buf[n];
    const float* __restrict__ xrow = Xg + (size_t)n * 1600;

    // Y[k][j] = sc2 * sum_c s(X[k][c]) * W1l[l(k)][c][j]
    float Ya[25], Yb[25];
#pragma unroll
    for (int k = 0; k < 25; ++k) { Ya[k] = 0.f; Yb[k] = 0.f; }
#pragma unroll 4
    for (int c = 0; c < 64; ++c) {
        float w0l[5], w1l[5];
#pragma unroll
        for (int l = 0; l < 5; ++l) {
            w0l[l] = W1l[l * 8192 + c * 128 + lane];
            w1l[l] = W1l[l * 8192 + c * 128 + 64 + lane];
        }
#pragma unroll
        for (int k = 0; k < 25; ++k) {
            const float xv = xrow[k * 64 + c];   // wave-uniform -> scalar pipe
            Ya[k] += xv * w0l[lpk(k)];
            Yb[k] += xv * w1l[lpk(k)];
        }
    }
#pragma unroll
    for (int k = 0; k < 25; ++k) { Ya[k] *= sc2; Yb[k] *= sc2; }

    // g-loop: h = silu(tg.Y); U += fg*h   (all lane=j, pure s x v FMA)
    float Ua[25], Ub[25];
#pragma unroll
    for (int k = 0; k < 25; ++k) { Ua[k] = 0.f; Ub[k] = 0.f; }
#pragma unroll 2
    for (int g = 0; g < GG; ++g) {
        const float* __restrict__ tg = to_grid + (size_t)g * KK;
        const float* __restrict__ fg = fgT + (size_t)g * KK;
        float ha = 0.f, hb = 0.f;
#pragma unroll
        for (int k = 0; k < 25; ++k) {
            const float t = tg[k];
            ha += t * Ya[k];
            hb += t * Yb[k];
        }
        ha = siluf(ha); hb = siluf(hb);
#pragma unroll
        for (int k = 0; k < 25; ++k) {
            const float f = fg[k];
            Ua[k] += f * ha;
            Ub[k] += f * hb;
        }
    }

    // store U in [n][j][k] layout (rows of 25 for k_ffn2's s_loads)
    float* __restrict__ ua = Uws + ((size_t)n * 128 + lane) * 25;
    float* __restrict__ ub = Uws + ((size_t)n * 128 + 64 + lane) * 25;
#pragma unroll
    for (int k = 0; k < 25; ++k) {
        ua[k] = Ua[k];
        ub[k] = Ub[k];
    }
}

// ---- k_ffn2: wave-per-node (lane=c). racc = sum_j s(U[j][k]) * Wf2[j][c];
// out = X + racc -- zero rdl. ----
__global__ __launch_bounds__(256) void k_ffn2(
        const float* __restrict__ Uws, const float* __restrict__ Wf2,
        float* __restrict__ out, int N) {
    const int lane = threadIdx.x & 63;
    const int n = __builtin_amdgcn_readfirstlane(blockIdx.x * 4 + (threadIdx.x >> 6));
    if (n >= N) return;
    const float* __restrict__ urow = Uws + (size_t)n * 3200;
    float racc[25];
#pragma unroll
    for (int k = 0; k < 25; ++k) racc[k] = 0.f;
#pragma unroll 2
    for (int j = 0; j < 128; ++j) {
        const float wv = Wf2[j * 64 + lane];
        const float* __restrict__ up = urow + j * 25;
#pragma unroll
        for (int k = 0; k < 25; ++k) racc[k] += up[k] * wv;
    }
    float* __restrict__ op = out + (size_t)n * 1600;
#pragma unroll
    for (int k = 0; k < 25; ++k)
        op[k * 64 + lane] = op[k * 64 + lane] + racc[k];
}

// ---- k_ffn (fallback, round-4 verified) ----
__global__ __launch_bounds__(256) void k_ffn(
        const float* __restrict__ xf, const float* __restrict__ g2,
        const float* __restrict__ to_grid, const float* __restrict__ fgT,
        const float* __restrict__ Wf1, const float* __restrict__ Wf2,
        float* __restrict__ out, int N) {
    const int lane = threadIdx.x & 63;
    const int n = __builtin_amdgcn_readfirstlane(blockIdx.x * 4 + (threadIdx.x >> 6));
    if (n >= N) return;
    const float* __restrict__ oin = out + (size_t)n * 1600;
    const float* __restrict__ xin = xf + (size_t)n * 1600;

    float xn[25];
    float ss = 0.f;
#pragma unroll
    for (int k = 0; k < 25; ++k) {
        const float X = oin[k * 64 + lane] + xin[k * 64 + lane];
        xn[k] = X;
        ss += X * X;
    }
#pragma unroll
    for (int m = 1; m < 64; m <<= 1) ss += __shfl_xor(ss, m, 64);
    const float sc2 = rsqrtf(ss * (1.0f / 1600.f) + 1e-6f);
#pragma unroll
    for (int k = 0; k < 25; ++k) xn[k] *= sc2 * g2[lpk(k) * 64 + lane];

    float Ya[25], Yb[25];
#pragma unroll
    for (int k = 0; k < 25; ++k) { Ya[k] = 0.f; Yb[k] = 0.f; }
    for (int c = 0; c < 64; ++c) {
        const float w0 = Wf1[c * FFH + lane];
        const float w1 = Wf1[c * FFH + 64 + lane];
#pragma unroll
        for (int k = 0; k < 25; ++k) {
            const float sv = rdlane(xn[k], c);
            Ya[k] += sv * w0;
            Yb[k] += sv * w1;
        }
    }

    float Ua[25], Ub[25];
#pragma unroll
    for (int k = 0; k < 25; ++k) { Ua[k] = 0.f; Ub[k] = 0.f; }
#pragma unroll 2
    for (int g = 0; g < GG; ++g) {
        const float* __restrict__ tg = to_grid + (size_t)g * KK;
        const float* __restrict__ fg = fgT + (size_t)g * KK;
        float ha = 0.f, hb = 0.f;
#pragma unroll
        for (int k = 0; k < 25; ++k) {
            const float t = tg[k];
            ha += t * Ya[k];
            hb += t * Yb[k];
        }
        ha = siluf(ha); hb = siluf(hb);
#pragma unroll
        for (int k = 0; k < 25; ++k) {
            const float f = fg[k];
            Ua[k] += f * ha;
            Ub[k] += f * hb;
        }
    }

    float racc[25];
#pragma unroll
    for (int k = 0; k < 25; ++k) racc[k] = 0.f;
    for (int j = 0; j < 64; ++j) {
        const float w0 = Wf2[j * 64 + lane];
        const float w1 = Wf2[(64 + j) * 64 + lane];
#pragma unroll
        for (int k = 0; k < 25; ++k)
            racc[k] += rdlane(Ua[k], j) * w0 + rdlane(Ub[k], j) * w1;
    }

    float* __restrict__ op = out + (size_t)n * 1600;
#pragma unroll
    for (int k = 0; k < 25; ++k)
        op[k * 64 + lane] = oin[k * 64 + lane] + xin[k * 64 + lane] + racc[k];
}

extern "C" void kernel_launch(void* const* d_in, const int* in_sizes, int n_in,
                              void* d_out, int out_size, void* d_ws, size_t ws_size,
                              hipStream_t stream) {
    const float* node_feats     = (const float*)d_in[0];
    const float* edge_distances = (const float*)d_in[1];
    const float* wigner         = (const float*)d_in[2];
    const float* wigner_inv     = (const float*)d_in[3];
    const int*   node_species   = (const int*)  d_in[4];
    const int*   senders        = (const int*)  d_in[5];
    const int*   receivers      = (const int*)  d_in[6];
    const float* g1             = (const float*)d_in[7];
    const float* g2             = (const float*)d_in[8];
    const float* emb_s          = (const float*)d_in[9];
    const float* emb_r          = (const float*)d_in[10];
    const float* We1            = (const float*)d_in[11];
    const float* We2            = (const float*)d_in[12];
    const float* Wso2           = (const float*)d_in[13];
    const float* Wa             = (const float*)d_in[14];
    const float* va             = (const float*)d_in[15];
    const float* Wv             = (const float*)d_in[16];
    const float* Wo             = (const float*)d_in[17];
    const float* to_grid        = (const float*)d_in[18];
    const float* from_grid      = (const float*)d_in[19];
    const float* Wf1            = (const float*)d_in[20];
    const float* Wf2            = (const float*)d_in[21];

    const int N = in_sizes[4];
    const int E = in_sizes[5];

    char* ws = (char*)d_ws;
    size_t o = 0;
    float* scale    = (float*)(ws + o); o += (size_t)N * 4;
    int*   counts   = (int*)  (ws + o); o += (size_t)N * 4;
    int*   offsets  = (int*)  (ws + o); o += (size_t)(N + 1) * 4;
    int*   edge_ids = (int*)  (ws + o); o += (size_t)E * 4;
    float* logits   = (float*)(ws + o); o += (size_t)E * NH * 4;
    float* fgT      = (float*)(ws + o); o += (size_t)GG * KK * 4;
    // fast-path buffers (gated on ws_size)
    size_t o_fast = o;
    float* efsbuf = (float*)(ws + o_fast); o_fast += (size_t)E * 64 * 4;
    float* Wvo    = (float*)(ws + o_fast); o_fast += (size_t)4 * 64 * 64 * 4;
    float* pq     = (float*)(ws + o_fast); o_fast += (size_t)N * 3200 * 4; // reused as Uws
    float* W1l    = (float*)(ws + o_fast); o_fast += (size_t)5 * 64 * 128 * 4;
    float* sc2    = (float*)(ws + o_fast); o_fast += (size_t)N * 4;
    const bool fast = (ws_size >= o_fast);

    hipMemsetAsync(counts, 0, (size_t)N * 4, stream);
    hipMemsetAsync(d_out, 0, (size_t)N * 1600 * 4, stream);

    k_tr_fg<<<(GG * KK + 255) / 256, 256, 0, stream>>>(from_grid, fgT);
    if (fast) {
        k_pq<<<(N + 3) / 4, 256, 0, stream>>>(node_feats, g1, Wso2, pq, N);
        k_wvo<<<64, 256, 0, stream>>>(Wv, Wo, Wvo);
        k_w1l<<<(5 * 64 * 128 + 255) / 256, 256, 0, stream>>>(g2, Wf1, W1l);
        k_elog<<<(E + 3) / 4, 256, 0, stream>>>(edge_distances, emb_s, emb_r, We1,
                                                We2, Wa, va, pq, wigner, node_species,
                                                senders, receivers, logits, efsbuf,
                                                N, E);
        k_count<<<(E + 255) / 256, 256, 0, stream>>>(receivers, counts, E);
        k_scan<<<1, 256, 0, stream>>>(counts, offsets, N);
        k_fill<<<(E + 255) / 256, 256, 0, stream>>>(receivers, offsets, counts,
                                                    edge_ids, E);
        k_alpha<<<(N * NH + 255) / 256, 256, 0, stream>>>(logits, offsets, edge_ids, N);
        k_edge_fast<<<(E + 3) / 4, 256, 0, stream>>>(pq, wigner, wigner_inv, Wvo,
                                                     efsbuf, logits, senders, receivers,
                                                     (float*)d_out, N, E);
        // FFN: X := attn_out + residual (in d_out), then factorized grid FFN
        k_rms<<<N, 256, 0, stream>>>(node_feats, (float*)d_out, sc2);
        k_ffn1<<<(N + 3) / 4, 256, 0, stream>>>((const float*)d_out, sc2, W1l,
                                                to_grid, fgT, pq, N);
        k_ffn2<<<(N + 3) / 4, 256, 0, stream>>>(pq, Wf2, (float*)d_out, N);
    } else {
        k_scale<<<N, 256, 0, stream>>>(node_feats, scale);
        k_edge_logits<<<E, 128, 0, stream>>>(edge_distances, emb_s, emb_r, We1, We2,
                                             Wso2, Wa, va, wigner, node_feats, g1,
                                             scale, node_species, senders, receivers,
                                             logits);
        k_count<<<(E + 255) / 256, 256, 0, stream>>>(receivers, counts, E);
        k_scan<<<1, 256, 0, stream>>>(counts, offsets, N);
        k_fill<<<(E + 255) / 256, 256, 0, stream>>>(receivers, offsets, counts,
                                                    edge_ids, E);
        k_alpha<<<(N * NH + 255) / 256, 256, 0, stream>>>(logits, offsets, edge_ids, N);
        k_edge<<<(E + 3) / 4, 256, 0, stream>>>(node_feats, wigner, wigner_inv,
                                                edge_distances, emb_s, emb_r, We1, We2,
                                                Wso2, Wv, Wo, g1, scale, logits,
                                                node_species, senders, receivers,
                                                (float*)d_out, E);
        k_ffn<<<(N + 3) / 4, 256, 0, stream>>>(node_feats, g2, to_grid, fgT, Wf1, Wf2,
                                               (float*)d_out, N);
    }
}